// Round 10
// baseline (3603.778 us; speedup 1.0000x reference)
//
#include <hip/hip_runtime.h>
#include <hip/hip_bf16.h>

#define DEV __device__ __forceinline__

DEV float bf2f(unsigned short u){ return __uint_as_float(((unsigned)u)<<16); }
DEV unsigned short f2bf(float f){
  unsigned u = __float_as_uint(f);
  u += 0x7fffu + ((u>>16)&1u);   // RNE
  return (unsigned short)(u>>16);
}

// DPP-based u64 max step: permute both halves identically, umax with self as
// fallback (identity). ctrl: 0x110|N=row_shr:N, 0x142=row_bcast15, 0x143=row_bcast31.
template<int CTRL>
DEV unsigned long long dpp_umax(unsigned long long k){
  int lo = (int)(unsigned)k;
  int hi = (int)(unsigned)(k>>32);
  int plo = __builtin_amdgcn_update_dpp(lo, lo, CTRL, 0xF, 0xF, false);
  int phi = __builtin_amdgcn_update_dpp(hi, hi, CTRL, 0xF, 0xF, false);
  unsigned long long p = ((unsigned long long)(unsigned)phi << 32) | (unsigned)plo;
  return (p > k) ? p : k;
}

// ---------------------------------------------------------------------------
// dtype detection: genuine bf16 N(0,1) data never has exponent >= 0xC0;
// fp32 read as ushorts has ~25% such halfwords. flag=1 -> inputs fp32.
__global__ __launch_bounds__(256) void detect_kernel(
    const unsigned short* __restrict__ x, int* __restrict__ flag){
  __shared__ int cnt;
  if (threadIdx.x==0) cnt = 0;
  __syncthreads();
  int local = 0;
  for (int i=threadIdx.x; i<4096; i+=256){
    int e = (x[i]>>7)&0xFF;
    if (e >= 0xC0) local++;
  }
  atomicAdd(&cnt, local);
  __syncthreads();
  if (threadIdx.x==0) *flag = (cnt > 64) ? 1 : 0;
}

// ---------------------------------------------------------------------------
struct PConv {
  const void* s[14];
  float*      d[14];
  int         sz[14];
};
__global__ __launch_bounds__(256) void conv_params_kernel(PConv p, const int* __restrict__ flag){
  bool isf = (*flag != 0);
  int i = blockIdx.x*256 + threadIdx.x;
  int seg = 0, off = i;
  #pragma unroll
  for (seg=0; seg<14; ++seg){
    if (off < p.sz[seg]) break;
    off -= p.sz[seg];
  }
  if (seg >= 14) return;
  float v = isf ? ((const float*)p.s[seg])[off]
                : bf2f(((const unsigned short*)p.s[seg])[off]);
  p.d[seg][off] = v;
}

// ---------------------------------------------------------------------------
// prep: coords (B,3,2048)->(B,2048,3) fp32, f0 = w_in@x + b_in, zero stats(8192).
__global__ __launch_bounds__(256) void prep_kernel(
    const void* __restrict__ xraw, const int* __restrict__ flag,
    const float* __restrict__ w_in, const float* __restrict__ b_in,
    float* __restrict__ xyz0, float* __restrict__ f0, float* __restrict__ stats){
  int i = blockIdx.x*256 + threadIdx.x;          // 32*2048 threads
  if (i < 8192) stats[i] = 0.f;
  bool isf = (*flag != 0);
  int b = i >> 11, n = i & 2047;
  size_t base = (size_t)b*3*2048 + n;
  float X, Y, Z;
  if (isf){
    const float* xf = (const float*)xraw;
    X = xf[base]; Y = xf[base+2048]; Z = xf[base+4096];
  } else {
    const unsigned short* xu = (const unsigned short*)xraw;
    X = bf2f(xu[base]); Y = bf2f(xu[base+2048]); Z = bf2f(xu[base+4096]);
  }
  float* o3 = xyz0 + (size_t)i*3;
  o3[0]=X; o3[1]=Y; o3[2]=Z;
  float* fo = f0 + (size_t)i*8;
  #pragma unroll
  for (int o=0;o<8;++o){
    fo[o] = w_in[o*3+0]*X + w_in[o*3+1]*Y + w_in[o*3+2]*Z + b_in[o];
  }
}

// ---------------------------------------------------------------------------
// Split-K kNN body (256 threads): 4 threads/query, thread h scans m==h (mod 4),
// private sorted top-16 (strict-< insert => stable), leader 4-way lex merge.
// smem: >= max(NK*4, 130*QB) floats.
template<int NK, int QB>
DEV void knn_body(float* smem, const float* __restrict__ qxyz,
                  const float* __restrict__ kxyz, int Nq,
                  int* __restrict__ oidx, int bx, int b){
  float4* kd = (float4*)smem;
  int t = threadIdx.x;
  for (int i=t; i<NK; i+=256){
    const float* p = kxyz + ((size_t)b*NK + i)*3;
    float X=p[0], Y=p[1], Z=p[2];
    float sk = __fadd_rn(__fadd_rn(__fmul_rn(X,X),__fmul_rn(Y,Y)),__fmul_rn(Z,Z));
    kd[i] = make_float4(X,Y,Z,sk);
  }
  __syncthreads();
  int ql = t>>2, h = t&3;
  int q0 = bx*QB;
  const float* qp = qxyz + ((size_t)b*Nq + q0 + ql)*3;
  float QX=qp[0], QY=qp[1], QZ=qp[2];
  float sq = __fadd_rn(__fadd_rn(__fmul_rn(QX,QX),__fmul_rn(QY,QY)),__fmul_rn(QZ,QZ));
  float dl[16]; int il[16];
  #pragma unroll
  for (int j=0;j<16;++j){ dl[j]=3.4e38f; il[j]=-1; }
  for (int i=0; i<NK/4; i+=8){
    float d[8];
    #pragma unroll
    for (int u=0;u<8;++u){
      float4 c = kd[4*(i+u)+h];
      float dot = __fadd_rn(__fadd_rn(__fmul_rn(QX,c.x),__fmul_rn(QY,c.y)),__fmul_rn(QZ,c.z));
      d[u] = __fsub_rn(__fadd_rn(sq, c.w), __fmul_rn(2.0f,dot));
    }
    float dmin = fminf(fminf(fminf(d[0],d[1]),fminf(d[2],d[3])),
                       fminf(fminf(d[4],d[5]),fminf(d[6],d[7])));
    if (dmin < dl[15]){
      #pragma unroll
      for (int u=0;u<8;++u){
        float du = d[u];
        if (du < dl[15]){               // strict <: equal dist keeps earlier index
          dl[15]=du; il[15]=4*(i+u)+h;
          #pragma unroll
          for (int s=15;s>0;--s){
            if (dl[s] < dl[s-1]){       // strict <: stable among equals
              float td=dl[s]; dl[s]=dl[s-1]; dl[s-1]=td;
              int   ti=il[s]; il[s]=il[s-1]; il[s-1]=ti;
            }
          }
        }
      }
    }
  }
  __syncthreads();                       // kd reads done; reuse smem for lists
  float* dbuf = smem;
  int*   ibuf = (int*)(smem + QB*65);
  int base = ql*65 + h*16;
  #pragma unroll
  for (int j=0;j<16;++j){ dbuf[base+j]=dl[j]; ibuf[base+j]=il[j]; }
  __syncthreads();
  if (t < QB){
    const float* db = dbuf + t*65;
    const int*   ib = ibuf + t*65;
    int p0=0,p1=0,p2=0,p3=0;
    int* op = oidx + ((size_t)b*Nq + q0 + t)*16;
    #pragma unroll 1
    for (int j=0;j<16;++j){
      float e0 = (p0<16)? db[p0]    : 3.5e38f; int i0 = (p0<16)? ib[p0]    : 0x7fffffff;
      float e1 = (p1<16)? db[16+p1] : 3.5e38f; int i1 = (p1<16)? ib[16+p1] : 0x7fffffff;
      float e2 = (p2<16)? db[32+p2] : 3.5e38f; int i2 = (p2<16)? ib[32+p2] : 0x7fffffff;
      float e3 = (p3<16)? db[48+p3] : 3.5e38f; int i3 = (p3<16)? ib[48+p3] : 0x7fffffff;
      float bd=e0; int bi=i0; int bh=0;
      if (e1<bd || (e1==bd && i1<bi)){ bd=e1; bi=i1; bh=1; }
      if (e2<bd || (e2==bd && i2<bi)){ bd=e2; bi=i2; bh=2; }
      if (e3<bd || (e3==bd && i3<bi)){ bd=e3; bi=i3; bh=3; }
      op[j]=bi;
      p0 += (bh==0); p1 += (bh==1); p2 += (bh==2); p3 += (bh==3);
    }
  }
  __syncthreads();                       // safe smem handoff (fused callers)
}

// ---------------------------------------------------------------------------
// FPS, single-wave, BARRIER-FREE. One 64-lane wave owns a whole batch: no
// cross-wave merge, no __syncthreads in the serial loop (round-9 showed the
// 4-wave rendezvous was ~60% of step time). Coords in LDS as SoA (stride-4B:
// 2 lanes/bank = conflict-free, m136) via VOLATILE pointers so the compiler
// cannot hoist the loop-invariant reads into 96+ registers (round-6 spill
// failure mode); only dist[PPT] lives in registers. Argmax via packed u64
// key (fbits(dist)<<32)|(~idx): umax == lex (dist desc, idx asc) == ref
// tie-break; DPP row_shr/bcast chain + readlane. Same-wave LDS ops complete
// in issue order, so init-writes -> reads needs no barrier. Exact no-FMA.
// Caller must ensure only threads 0..63 enter. smem: 3*NP + G floats.
template<int NP,int G>
DEV void fps_body_sw(float* smem, const float* __restrict__ xyz,
                     int* __restrict__ oidx, float* __restrict__ oxyz, int b){
  constexpr int PPT = NP/64;
  volatile float* xs = smem;
  volatile float* ys = smem + NP;
  volatile float* zs = smem + 2*NP;
  int* selidx = (int*)(smem + 3*NP);
  int t = threadIdx.x;                 // 0..63
  float dist[PPT];
  #pragma unroll
  for (int j=0;j<PPT;++j){
    int gi = t + j*64;
    const float* p = xyz + ((size_t)b*NP + gi)*3;
    xs[gi]=p[0]; ys[gi]=p[1]; zs[gi]=p[2];
    dist[j]=1e10f;
  }
  if (t==0) selidx[0]=0;
  float cx = xs[0], cy = ys[0], cz = zs[0];
  int Bi = 0;
  for (int g=1; g<G; ++g){
    float bv=-1.f; int bi=0x7fffffff;
    #pragma unroll
    for (int j=0;j<PPT;++j){
      int gi = t + j*64;
      float dx=__fsub_rn(xs[gi],cx), dy=__fsub_rn(ys[gi],cy), dz=__fsub_rn(zs[gi],cz);
      float d = __fadd_rn(__fadd_rn(__fmul_rn(dx,dx),__fmul_rn(dy,dy)),__fmul_rn(dz,dz));
      float nd = fminf(dist[j], d);
      dist[j]=nd;
      bool cc = (nd > bv);             // ascending gi in-lane: first-max kept
      bv = cc ? nd : bv;
      bi = cc ? gi : bi;
    }
    unsigned long long k =
      ((unsigned long long)__float_as_uint(bv)<<32) | (unsigned)(0xFFFFFFFFu - bi);
    k = dpp_umax<0x111>(k);            // row_shr:1
    k = dpp_umax<0x112>(k);            // row_shr:2
    k = dpp_umax<0x114>(k);            // row_shr:4
    k = dpp_umax<0x118>(k);            // row_shr:8
    k = dpp_umax<0x142>(k);            // row_bcast15
    k = dpp_umax<0x143>(k);            // row_bcast31 -> lane 63 has wave max
    unsigned klo = (unsigned)__builtin_amdgcn_readlane((int)(unsigned)k, 63);
    Bi = (int)(0xFFFFFFFFu - klo);     // uniform in all lanes
    cx = xs[Bi]; cy = ys[Bi]; cz = zs[Bi];   // uniform broadcast reads
    if (t==0) selidx[g]=Bi;
  }
  for (int i=t; i<G; i+=64){
    int s = selidx[i];
    oidx[(size_t)b*G + i] = s;
    float* op = oxyz + ((size_t)b*G + i)*3;
    op[0]=xs[s]; op[1]=ys[s]; op[2]=zs[s];
  }
}

// ---------------------------------------------------------------------------
// EdgeConv pre-norm body (256 threads). See round-3 notes; smem-pointer form
// so it can run inside fused kernels. smem floats: WTB + QB*ESTR + QB*CF + 8.
template<int CF,int COUT,int QB>
DEV void edge_body(float* smem, const float* __restrict__ fk,
                   const int* __restrict__ sel, const int* __restrict__ knn,
                   const float* __restrict__ w, float* __restrict__ mm,
                   float* __restrict__ stats, int Nq, int Nk, int bx, int b){
  constexpr int CIN = 2*CF;
  constexpr int GPQ = COUT/2;
  constexpr int WS  = COUT+1;
  constexpr int ESTR= CF*16+8;
  constexpr int WTB = ((CF*WS+3)&~3);
  static_assert(QB*GPQ == 256, "block mapping");
  float* wtb = smem;                  // CF*WS
  float* e   = smem + WTB;            // QB*ESTR (16B aligned)
  float* fqs = e + QB*ESTR;           // QB*CF
  float* sS  = fqs + QB*CF;           // 8
  int t = threadIdx.x;
  int q0 = bx*QB;

  if (t<8) sS[t]=0.f;
  for (int i=t; i<QB*CF; i+=256){
    int ql = i/CF, c = i&(CF-1);
    int qi = sel ? sel[b*Nq + q0 + ql] : (q0 + ql);
    fqs[i] = fk[((size_t)b*Nk + qi)*CF + c];
  }
  // stage weight half A (c < CF)
  for (int i=t; i<CF*COUT; i+=256){
    int o = i/CF, c = i&(CF-1);
    wtb[c*WS+o] = w[o*CIN + c];
  }
  if (t < QB*16){
    int ql = t>>4, k = t&15;
    int nid = knn[((size_t)b*Nq + q0 + ql)*16 + k];
    const float4* row = (const float4*)(fk + ((size_t)b*Nk + nid)*CF);
    float* ep = e + ql*ESTR + k;
    #pragma unroll
    for (int c4=0; c4<CF/4; ++c4){
      float4 v = row[c4];
      ep[(c4*4+0)*16]=v.x; ep[(c4*4+1)*16]=v.y; ep[(c4*4+2)*16]=v.z; ep[(c4*4+3)*16]=v.w;
    }
  }
  __syncthreads();

  int ql = t/GPQ, o = t%GPQ;
  const float* eb = e + ql*ESTR;
  const float* fqb = fqs + ql*CF;
  float y0[16], y1[16];
  #pragma unroll
  for (int k=0;k<16;++k){ y0[k]=0.f; y1[k]=0.f; }
  float zA0=0.f, zA1=0.f;
  for (int c=0;c<CF;++c){
    float w0 = wtb[c*WS+o];
    float w1 = wtb[c*WS+o+GPQ];
    float fqc = fqb[c];
    zA0 = fmaf(w0,fqc,zA0); zA1 = fmaf(w1,fqc,zA1);
    const float4* ev4 = (const float4*)(eb + c*16);
    #pragma unroll
    for (int k4=0;k4<4;++k4){
      float4 ev = ev4[k4];
      y0[k4*4+0]=fmaf(w0,ev.x,y0[k4*4+0]); y0[k4*4+1]=fmaf(w0,ev.y,y0[k4*4+1]);
      y0[k4*4+2]=fmaf(w0,ev.z,y0[k4*4+2]); y0[k4*4+3]=fmaf(w0,ev.w,y0[k4*4+3]);
      y1[k4*4+0]=fmaf(w1,ev.x,y1[k4*4+0]); y1[k4*4+1]=fmaf(w1,ev.y,y1[k4*4+1]);
      y1[k4*4+2]=fmaf(w1,ev.z,y1[k4*4+2]); y1[k4*4+3]=fmaf(w1,ev.w,y1[k4*4+3]);
    }
  }
  __syncthreads();
  // stage weight half B (c >= CF)
  for (int i=t; i<CF*COUT; i+=256){
    int oo = i/CF, c = i&(CF-1);
    wtb[c*WS+oo] = w[oo*CIN + CF + c];
  }
  __syncthreads();
  float zB0=0.f, zB1=0.f;
  for (int c=0;c<CF;++c){
    float fqc = fqb[c];
    zB0 = fmaf(wtb[c*WS+o],fqc,zB0);
    zB1 = fmaf(wtb[c*WS+o+GPQ],fqc,zB1);
  }
  float z0 = zB0 - zA0, z1 = zB1 - zA1;

  float mx0=-3.4e38f, mn0=3.4e38f, s0=0.f, q0s=0.f;
  float mx1=-3.4e38f, mn1=3.4e38f, s1=0.f, q1s=0.f;
  #pragma unroll
  for (int k=0;k<16;++k){
    float v0 = y0[k]+z0, v1 = y1[k]+z1;
    mx0=fmaxf(mx0,v0); mn0=fminf(mn0,v0); s0+=v0; q0s=fmaf(v0,v0,q0s);
    mx1=fmaxf(mx1,v1); mn1=fminf(mn1,v1); s1+=v1; q1s=fmaf(v1,v1,q1s);
  }
  int g0 = o/(COUT/4);
  atomicAdd(&sS[g0],   s0); atomicAdd(&sS[4+g0],   q0s);
  atomicAdd(&sS[g0+2], s1); atomicAdd(&sS[6+g0],   q1s);
  size_t mi0 = ((size_t)b*Nq + q0 + ql)*COUT + o;
  ((float2*)mm)[mi0]       = make_float2(mx0,mn0);
  ((float2*)mm)[mi0+GPQ]   = make_float2(mx1,mn1);
  __syncthreads();
  if (t<8){
    int g = t>>1, which = t&1;
    float val = which ? sS[4+g] : sS[g];
    atomicAdd(&stats[(((size_t)b*4+g)*8 + (bx&7))*2 + which], val);
  }
}

// ---------------------------------------------------------------------------
// Fused launches: FPS blocks first (grab CU slots immediately); independent
// knn/edge work fills the rest. Events are banned -> only overlap path.
// fps blocks use one wave; their other 3 waves exit at once (no barriers in
// the fps path, so early exit is safe).
__global__ __launch_bounds__(256,4) void fused1_kernel(
    const float* __restrict__ xyz0, int* __restrict__ knnb1,
    int* __restrict__ idx1, float* __restrict__ xyz1){
  __shared__ __align__(16) float smem[8320];   // knn 8320 > fps1 6656
  int bx = blockIdx.x;
  if (bx < 32){
    if (threadIdx.x >= 64) return;
    fps_body_sw<2048,512>(smem, xyz0, idx1, xyz1, bx);
  } else {
    int rid = bx - 32;                          // 1024 knn1 blocks
    knn_body<2048,64>(smem, xyz0, xyz0, 2048, knnb1, rid & 31, rid >> 5);
  }
}

__global__ __launch_bounds__(256,4) void fused2_kernel(
    const float* __restrict__ xyz0, const float* __restrict__ xyz1,
    const int* __restrict__ knnb1,
    int* __restrict__ knnb2, int* __restrict__ knnb3,
    int* __restrict__ idx2, float* __restrict__ xyz2,
    const float* __restrict__ f0, const float* __restrict__ cw1,
    float* __restrict__ mmb, float* __restrict__ stats1){
  __shared__ __align__(16) float smem[8320];   // knn 8320 > edge1 2576 > fps2 1664
  int bx = blockIdx.x;
  if (bx < 32){
    if (threadIdx.x >= 64) return;
    fps_body_sw<512,128>(smem, xyz1, idx2, xyz2, bx);
  } else if (bx < 288){
    int rid = bx - 32;                          // 256 knn2 blocks
    knn_body<2048,64>(smem, xyz1, xyz0, 512, knnb2, rid & 7, rid >> 3);
  } else if (bx < 544){
    int rid = bx - 288;                         // 256 knn3 blocks
    knn_body<512,64>(smem, xyz1, xyz1, 512, knnb3, rid & 7, rid >> 3);
  } else {
    int rid = bx - 544;                         // 4096 edge1 blocks
    edge_body<8,32,16>(smem, f0, nullptr, knnb1, cw1, mmb, stats1,
                       2048, 2048, rid & 127, rid >> 7);
  }
}

template<int NK,int QB>
__global__ __launch_bounds__(QB*4,4) void knn_kernel(
    const float* __restrict__ qxyz, const float* __restrict__ kxyz,
    int Nq, int* __restrict__ oidx){
  constexpr int SM = (NK*4 > 130*QB) ? NK*4 : 130*QB;
  __shared__ __align__(16) float smem[SM];
  knn_body<NK,QB>(smem, qxyz, kxyz, Nq, oidx, blockIdx.x, blockIdx.y);
}

template<int CF,int COUT,int QB>
__global__ __launch_bounds__(256) void edge_kernel(
    const float* __restrict__ fk, const int* __restrict__ sel,
    const int* __restrict__ knn, const float* __restrict__ w,
    float* __restrict__ mm, float* __restrict__ stats, int Nq, int Nk){
  constexpr int WS  = COUT+1;
  constexpr int ESTR= CF*16+8;
  constexpr int WTB = ((CF*WS+3)&~3);
  constexpr int SM  = WTB + QB*ESTR + QB*CF + 8;
  __shared__ __align__(16) float smem[SM];
  edge_body<CF,COUT,QB>(smem, fk, sel, knn, w, mm, stats, Nq, Nk,
                        blockIdx.x, blockIdx.y);
}

// ---------------------------------------------------------------------------
// finalize: sum stat buckets, GN affine on max (min if a<0) + LeakyReLU.
__global__ __launch_bounds__(256) void fin_kernel(
    const float* __restrict__ mm, const float* __restrict__ stats,
    const float* __restrict__ gam, const float* __restrict__ bet,
    float* __restrict__ fo, void* __restrict__ outbase, const int* __restrict__ flag,
    int outoff, int Nq, int COUT, float invcnt, int total){
  for (int i = blockIdx.x*256 + threadIdx.x; i<total; i += gridDim.x*256){
    int o = i % COUT;
    int r = i / COUT;
    int q = r % Nq;
    int b = r / Nq;
    int g = o / (COUT>>2);
    const float* sp = stats + ((size_t)(b*4+g))*16;
    float s=0.f, s2=0.f;
    #pragma unroll
    for (int nb=0;nb<8;++nb){ s += sp[nb*2]; s2 += sp[nb*2+1]; }
    float mean = s*invcnt;
    float var  = fmaxf(s2*invcnt - mean*mean, 0.f);
    float inv  = 1.0f / sqrtf(var + 1e-5f);
    float a  = gam[o] * inv;
    float bb = bet[o] - a*mean;
    const float* mp = mm + (size_t)i*2;
    float xv = (a>=0.f) ? mp[0] : mp[1];  // monotone affine: max commutes
    float v = fmaf(a, xv, bb);
    v = (v>=0.f) ? v : 0.2f*v;
    if (fo) fo[i]=v;
    if (outbase){
      int idx = outoff + ((b*COUT + o)*Nq + q);
      if (*flag) ((float*)outbase)[idx] = v;
      else       ((unsigned short*)outbase)[idx] = f2bf(v);
    }
  }
}

__global__ __launch_bounds__(256) void coor_kernel(
    const float* __restrict__ xyz2, void* __restrict__ outbase,
    const int* __restrict__ flag){
  int i = blockIdx.x*256+threadIdx.x;   // 32*3*128
  int m = i & 127;
  int c = (i>>7) % 3;
  int b = i / 384;
  float v = xyz2[((size_t)b*128+m)*3 + c];
  if (*flag) ((float*)outbase)[i] = v;
  else       ((unsigned short*)outbase)[i] = f2bf(v);
}

// ---------------------------------------------------------------------------
extern "C" void kernel_launch(void* const* d_in, const int* in_sizes, int n_in,
                              void* d_out, int out_size, void* d_ws, size_t ws_size,
                              hipStream_t stream){
  float* W    = (float*)d_ws;
  float* xyz0 = W;                      // 196608
  float* f0   = W + 196608;             // 524288
  float* f1   = W + 720896;             // 2097152
  float* xyz1 = W + 2818048;            // 49152
  float* f2   = W + 2867200;            // 1048576
  float* f3   = W + 3915776;            // 1048576
  float* xyz2 = W + 4964352;            // 12288
  float* stats= W + 4976640;            // 8192 (4 layers x 32 x 4 x 8buckets x 2)
  int*   flag = (int*)(W + 4984832);    // 16 (pad)
  float* PRM  = W + 4984848;            // 29792 canonical fp32 params
  int*  idx1  = (int*)(W + 5014640);    // 16384
  int*  idx2  = (int*)(W + 5031024);    // 4096
  float* SCR  = W + 5035120;            // aliased per-layer scratch
  int*   knnb = (int*)SCR;              // knn1: 1048576 ints (dead after fused2)
  int*   knnb4= (int*)SCR;              // knn4 reuses knn1 region (65536 ints)
  int*   knnb2= (int*)f3;               // knn2: 262144 ints in f3 (dead at fin3)
  int*   knnb3= (int*)f3 + 262144;      // knn3: 262144 ints in f3
  float* mmb  = SCR + 1048576;          // <= 4194304 floats
  // total ~ 41.1 MB (unchanged)

  float* cw_in = PRM;          // 24
  float* cb_in = PRM+24;       // 8
  float* cw1 = PRM+32;   float* cg1 = PRM+544;   float* cbb1 = PRM+576;   // 512,32,32
  float* cw2 = PRM+608;  float* cg2 = PRM+4704;  float* cbb2 = PRM+4768;  // 4096,64,64
  float* cw3 = PRM+4832; float* cg3 = PRM+13024; float* cbb3 = PRM+13088; // 8192,64,64
  float* cw4 = PRM+13152;float* cg4 = PRM+29536; float* cbb4 = PRM+29664; // 16384,128,128

  detect_kernel<<<1,256,0,stream>>>((const unsigned short*)d_in[0], flag);

  PConv pc;
  const int psz[14] = {24,8,512,32,32,4096,64,64,8192,64,64,16384,128,128};
  float* pdst[14] = {cw_in,cb_in,cw1,cg1,cbb1,cw2,cg2,cbb2,cw3,cg3,cbb3,cw4,cg4,cbb4};
  for (int j=0;j<14;++j){ pc.s[j]=d_in[j+1]; pc.d[j]=pdst[j]; pc.sz[j]=psz[j]; }
  conv_params_kernel<<<117,256,0,stream>>>(pc, flag);

  prep_kernel<<<256,256,0,stream>>>(d_in[0], flag, cw_in, cb_in, xyz0, f0, stats);

  // ---- fused1: FPS 2048->512 (32 single-wave blocks) || knn1 (1024 blocks)
  fused1_kernel<<<1056,256,0,stream>>>(xyz0, knnb, idx1, xyz1);

  // ---- fused2: FPS 512->128 (32) || knn2 (256) || knn3 (256) || edge1 (4096)
  fused2_kernel<<<4640,256,0,stream>>>(xyz0, xyz1, knnb, knnb2, knnb3,
                                       idx2, xyz2, f0, cw1, mmb, stats+0);

  // ---- layer 1 finalize
  fin_kernel<<<1024,256,0,stream>>>(mmb, stats+0, cg1, cbb1, f1, nullptr, flag, 0, 2048, 32, 1.f/262144.f, 2097152);

  // ---- layer 2: 512q/2048k, 64 -> 64 (queries gathered via idx1)
  edge_kernel<32,64,8><<<dim3(64,32),256,0,stream>>>(f1, idx1, knnb2, cw2, mmb, stats+2048, 512, 2048);
  fin_kernel<<<1024,256,0,stream>>>(mmb, stats+2048, cg2, cbb2, f2, nullptr, flag, 0, 512, 64, 1.f/131072.f, 1048576);

  // ---- layer 3: 512q/512k, 128 -> 64
  edge_kernel<64,64,8><<<dim3(64,32),256,0,stream>>>(f2, nullptr, knnb3, cw3, mmb, stats+4096, 512, 512);
  fin_kernel<<<1024,256,0,stream>>>(mmb, stats+4096, cg3, cbb3, f3, nullptr, flag, 0, 512, 64, 1.f/131072.f, 1048576);

  // ---- layer 4: 128q/512k, 128 -> 128 (queries via idx2) -> final f output
  knn_kernel<512,64><<<dim3(2,32),256,0,stream>>>(xyz2, xyz1, 128, knnb4);
  edge_kernel<64,128,4><<<dim3(32,32),256,0,stream>>>(f3, idx2, knnb4, cw4, mmb, stats+6144, 128, 512);
  fin_kernel<<<1024,256,0,stream>>>(mmb, stats+6144, cg4, cbb4, nullptr, d_out, flag, 12288, 128, 128, 1.f/65536.f, 524288);

  // ---- coor output (B,3,128)
  coor_kernel<<<48,256,0,stream>>>(xyz2, d_out, flag);
}

// Round 11
// 766.596 us; speedup vs baseline: 4.7010x; 4.7010x over previous
//
#include <hip/hip_runtime.h>
#include <hip/hip_bf16.h>

#define DEV __device__ __forceinline__

DEV float bf2f(unsigned short u){ return __uint_as_float(((unsigned)u)<<16); }
DEV unsigned short f2bf(float f){
  unsigned u = __float_as_uint(f);
  u += 0x7fffu + ((u>>16)&1u);   // RNE
  return (unsigned short)(u>>16);
}

// DPP-based u64 max step: permute both halves identically, umax with self as
// fallback (identity). ctrl: 0x110|N=row_shr:N, 0x142=row_bcast15, 0x143=row_bcast31.
template<int CTRL>
DEV unsigned long long dpp_umax(unsigned long long k){
  int lo = (int)(unsigned)k;
  int hi = (int)(unsigned)(k>>32);
  int plo = __builtin_amdgcn_update_dpp(lo, lo, CTRL, 0xF, 0xF, false);
  int phi = __builtin_amdgcn_update_dpp(hi, hi, CTRL, 0xF, 0xF, false);
  unsigned long long p = ((unsigned long long)(unsigned)phi << 32) | (unsigned)plo;
  return (p > k) ? p : k;
}

// ---------------------------------------------------------------------------
// dtype detection: genuine bf16 N(0,1) data never has exponent >= 0xC0;
// fp32 read as ushorts has ~25% such halfwords. flag=1 -> inputs fp32.
__global__ __launch_bounds__(256) void detect_kernel(
    const unsigned short* __restrict__ x, int* __restrict__ flag){
  __shared__ int cnt;
  if (threadIdx.x==0) cnt = 0;
  __syncthreads();
  int local = 0;
  for (int i=threadIdx.x; i<4096; i+=256){
    int e = (x[i]>>7)&0xFF;
    if (e >= 0xC0) local++;
  }
  atomicAdd(&cnt, local);
  __syncthreads();
  if (threadIdx.x==0) *flag = (cnt > 64) ? 1 : 0;
}

// ---------------------------------------------------------------------------
struct PConv {
  const void* s[14];
  float*      d[14];
  int         sz[14];
};
__global__ __launch_bounds__(256) void conv_params_kernel(PConv p, const int* __restrict__ flag){
  bool isf = (*flag != 0);
  int i = blockIdx.x*256 + threadIdx.x;
  int seg = 0, off = i;
  #pragma unroll
  for (seg=0; seg<14; ++seg){
    if (off < p.sz[seg]) break;
    off -= p.sz[seg];
  }
  if (seg >= 14) return;
  float v = isf ? ((const float*)p.s[seg])[off]
                : bf2f(((const unsigned short*)p.s[seg])[off]);
  p.d[seg][off] = v;
}

// ---------------------------------------------------------------------------
// prep: coords (B,3,2048)->(B,2048,3) fp32, f0 = w_in@x + b_in, zero stats(8192).
__global__ __launch_bounds__(256) void prep_kernel(
    const void* __restrict__ xraw, const int* __restrict__ flag,
    const float* __restrict__ w_in, const float* __restrict__ b_in,
    float* __restrict__ xyz0, float* __restrict__ f0, float* __restrict__ stats){
  int i = blockIdx.x*256 + threadIdx.x;          // 32*2048 threads
  if (i < 8192) stats[i] = 0.f;
  bool isf = (*flag != 0);
  int b = i >> 11, n = i & 2047;
  size_t base = (size_t)b*3*2048 + n;
  float X, Y, Z;
  if (isf){
    const float* xf = (const float*)xraw;
    X = xf[base]; Y = xf[base+2048]; Z = xf[base+4096];
  } else {
    const unsigned short* xu = (const unsigned short*)xraw;
    X = bf2f(xu[base]); Y = bf2f(xu[base+2048]); Z = bf2f(xu[base+4096]);
  }
  float* o3 = xyz0 + (size_t)i*3;
  o3[0]=X; o3[1]=Y; o3[2]=Z;
  float* fo = f0 + (size_t)i*8;
  #pragma unroll
  for (int o=0;o<8;++o){
    fo[o] = w_in[o*3+0]*X + w_in[o*3+1]*Y + w_in[o*3+2]*Z + b_in[o];
  }
}

// ---------------------------------------------------------------------------
// Split-K kNN body (256 threads): 4 threads/query, thread h scans m==h (mod 4),
// private sorted top-16 (strict-< insert => stable), leader 4-way lex merge.
// smem: >= max(NK*4, 130*QB) floats.
template<int NK, int QB>
DEV void knn_body(float* smem, const float* __restrict__ qxyz,
                  const float* __restrict__ kxyz, int Nq,
                  int* __restrict__ oidx, int bx, int b){
  float4* kd = (float4*)smem;
  int t = threadIdx.x;
  for (int i=t; i<NK; i+=256){
    const float* p = kxyz + ((size_t)b*NK + i)*3;
    float X=p[0], Y=p[1], Z=p[2];
    float sk = __fadd_rn(__fadd_rn(__fmul_rn(X,X),__fmul_rn(Y,Y)),__fmul_rn(Z,Z));
    kd[i] = make_float4(X,Y,Z,sk);
  }
  __syncthreads();
  int ql = t>>2, h = t&3;
  int q0 = bx*QB;
  const float* qp = qxyz + ((size_t)b*Nq + q0 + ql)*3;
  float QX=qp[0], QY=qp[1], QZ=qp[2];
  float sq = __fadd_rn(__fadd_rn(__fmul_rn(QX,QX),__fmul_rn(QY,QY)),__fmul_rn(QZ,QZ));
  float dl[16]; int il[16];
  #pragma unroll
  for (int j=0;j<16;++j){ dl[j]=3.4e38f; il[j]=-1; }
  for (int i=0; i<NK/4; i+=8){
    float d[8];
    #pragma unroll
    for (int u=0;u<8;++u){
      float4 c = kd[4*(i+u)+h];
      float dot = __fadd_rn(__fadd_rn(__fmul_rn(QX,c.x),__fmul_rn(QY,c.y)),__fmul_rn(QZ,c.z));
      d[u] = __fsub_rn(__fadd_rn(sq, c.w), __fmul_rn(2.0f,dot));
    }
    float dmin = fminf(fminf(fminf(d[0],d[1]),fminf(d[2],d[3])),
                       fminf(fminf(d[4],d[5]),fminf(d[6],d[7])));
    if (dmin < dl[15]){
      #pragma unroll
      for (int u=0;u<8;++u){
        float du = d[u];
        if (du < dl[15]){               // strict <: equal dist keeps earlier index
          dl[15]=du; il[15]=4*(i+u)+h;
          #pragma unroll
          for (int s=15;s>0;--s){
            if (dl[s] < dl[s-1]){       // strict <: stable among equals
              float td=dl[s]; dl[s]=dl[s-1]; dl[s-1]=td;
              int   ti=il[s]; il[s]=il[s-1]; il[s-1]=ti;
            }
          }
        }
      }
    }
  }
  __syncthreads();                       // kd reads done; reuse smem for lists
  float* dbuf = smem;
  int*   ibuf = (int*)(smem + QB*65);
  int base = ql*65 + h*16;
  #pragma unroll
  for (int j=0;j<16;++j){ dbuf[base+j]=dl[j]; ibuf[base+j]=il[j]; }
  __syncthreads();
  if (t < QB){
    const float* db = dbuf + t*65;
    const int*   ib = ibuf + t*65;
    int p0=0,p1=0,p2=0,p3=0;
    int* op = oidx + ((size_t)b*Nq + q0 + t)*16;
    #pragma unroll 1
    for (int j=0;j<16;++j){
      float e0 = (p0<16)? db[p0]    : 3.5e38f; int i0 = (p0<16)? ib[p0]    : 0x7fffffff;
      float e1 = (p1<16)? db[16+p1] : 3.5e38f; int i1 = (p1<16)? ib[16+p1] : 0x7fffffff;
      float e2 = (p2<16)? db[32+p2] : 3.5e38f; int i2 = (p2<16)? ib[32+p2] : 0x7fffffff;
      float e3 = (p3<16)? db[48+p3] : 3.5e38f; int i3 = (p3<16)? ib[48+p3] : 0x7fffffff;
      float bd=e0; int bi=i0; int bh=0;
      if (e1<bd || (e1==bd && i1<bi)){ bd=e1; bi=i1; bh=1; }
      if (e2<bd || (e2==bd && i2<bi)){ bd=e2; bi=i2; bh=2; }
      if (e3<bd || (e3==bd && i3<bi)){ bd=e3; bi=i3; bh=3; }
      op[j]=bi;
      p0 += (bh==0); p1 += (bh==1); p2 += (bh==2); p3 += (bh==3);
    }
  }
  __syncthreads();                       // safe smem handoff (fused callers)
}

// ---------------------------------------------------------------------------
// FPS body (256 threads, 4 waves, one barrier per step) — ROUND-9 version
// (known good; round-10's single-wave volatile-LDS variant serialized every
// coordinate read and regressed 8x — do not revisit without asm-level loads).
// Packed u64 argmax key (fbits(dist)<<32)|(~idx): umax == lex (dist desc,
// idx asc) == ref tie-break. Wave reduce = DPP chain to lane 63 + readlane.
// Winner coords carried through the scan; cross-wave merge via parity
// double-buffered LDS slots yields Bi AND the centroid.
// smem: NP*4 + 48 + G floats. Exact fp32 no-FMA math.
template<int NP,int G>
DEV void fps_body(float* smem, const float* __restrict__ xyz,
                  int* __restrict__ oidx, float* __restrict__ oxyz, int b){
  constexpr int PPT = NP/256;
  float4* xl4 = (float4*)smem;
  unsigned long long* candK = (unsigned long long*)(smem + NP*4);   // [8] (2 par x 4 waves)
  float4* candX = (float4*)(smem + NP*4 + 16);                      // [8]
  int* selidx = (int*)(smem + NP*4 + 48);                           // [G]
  int t = threadIdx.x, w = t>>6;
  float px[PPT], py[PPT], pz[PPT], dist[PPT];
  #pragma unroll
  for (int j=0;j<PPT;++j){
    int gi = t + j*256;
    const float* p = xyz + ((size_t)b*NP + gi)*3;
    float X=p[0], Y=p[1], Z=p[2];
    px[j]=X; py[j]=Y; pz[j]=Z; dist[j]=1e10f;
    xl4[gi] = make_float4(X,Y,Z,0.f);
  }
  if (t==0) selidx[0] = 0;
  __syncthreads();
  float4 c0 = xl4[0];
  float cx=c0.x, cy=c0.y, cz=c0.z;
  int Bi = 0;
  for (int g=1; g<G; ++g){
    float bv=-1.f; int bi=0; float bxc=0.f, byc=0.f, bzc=0.f;
    #pragma unroll
    for (int j=0;j<PPT;++j){
      float dx=__fsub_rn(px[j],cx), dy=__fsub_rn(py[j],cy), dz=__fsub_rn(pz[j],cz);
      float d = __fadd_rn(__fadd_rn(__fmul_rn(dx,dx),__fmul_rn(dy,dy)),__fmul_rn(dz,dz));
      float nd = fminf(dist[j], d);
      dist[j] = nd;
      bool cc = (nd > bv);               // ascending idx in-lane: first-max kept
      bv = cc ? nd : bv;
      bi = cc ? (t + j*256) : bi;
      bxc = cc ? px[j] : bxc; byc = cc ? py[j] : byc; bzc = cc ? pz[j] : bzc;
    }
    unsigned long long klocal =
        ((unsigned long long)__float_as_uint(bv) << 32) | (unsigned)(0xFFFFFFFFu - bi);
    unsigned long long k = klocal;
    k = dpp_umax<0x111>(k);              // row_shr:1
    k = dpp_umax<0x112>(k);              // row_shr:2
    k = dpp_umax<0x114>(k);              // row_shr:4
    k = dpp_umax<0x118>(k);              // row_shr:8
    k = dpp_umax<0x142>(k);              // row_bcast15
    k = dpp_umax<0x143>(k);              // row_bcast31 -> lane 63 has wave max
    unsigned klo = (unsigned)__builtin_amdgcn_readlane((int)(unsigned)k, 63);
    unsigned khi = (unsigned)__builtin_amdgcn_readlane((int)(unsigned)(k>>32), 63);
    unsigned long long wkey = ((unsigned long long)khi<<32) | klo;
    int par = g & 1;
    if (klocal == wkey){                 // exactly one lane per wave (idx in key)
      candK[par*4 + w] = wkey;
      candX[par*4 + w] = make_float4(bxc, byc, bzc, 0.f);
    }
    __syncthreads();
    unsigned long long kk = candK[par*4+0]; float4 xx = candX[par*4+0];
    unsigned long long k1 = candK[par*4+1]; float4 x1 = candX[par*4+1];
    if (k1 > kk){ kk=k1; xx=x1; }
    unsigned long long k2 = candK[par*4+2]; float4 x2 = candX[par*4+2];
    if (k2 > kk){ kk=k2; xx=x2; }
    unsigned long long k3 = candK[par*4+3]; float4 x3 = candX[par*4+3];
    if (k3 > kk){ kk=k3; xx=x3; }
    Bi = (int)(0xFFFFFFFFu - (unsigned)kk);
    cx = xx.x; cy = xx.y; cz = xx.z;
    if (t==0) selidx[g] = Bi;
  }
  __syncthreads();
  for (int i=t; i<G; i+=256){
    int s = selidx[i];
    float4 c = xl4[s];
    oidx[(size_t)b*G + i] = s;
    float* op = oxyz + ((size_t)b*G + i)*3;
    op[0]=c.x; op[1]=c.y; op[2]=c.z;
  }
}

// ---------------------------------------------------------------------------
// EdgeConv pre-norm body (256 threads). See round-3 notes; smem-pointer form
// so it can run inside fused kernels. smem floats: WTB + QB*ESTR + QB*CF + 8.
template<int CF,int COUT,int QB>
DEV void edge_body(float* smem, const float* __restrict__ fk,
                   const int* __restrict__ sel, const int* __restrict__ knn,
                   const float* __restrict__ w, float* __restrict__ mm,
                   float* __restrict__ stats, int Nq, int Nk, int bx, int b){
  constexpr int CIN = 2*CF;
  constexpr int GPQ = COUT/2;
  constexpr int WS  = COUT+1;
  constexpr int ESTR= CF*16+8;
  constexpr int WTB = ((CF*WS+3)&~3);
  static_assert(QB*GPQ == 256, "block mapping");
  float* wtb = smem;                  // CF*WS
  float* e   = smem + WTB;            // QB*ESTR (16B aligned)
  float* fqs = e + QB*ESTR;           // QB*CF
  float* sS  = fqs + QB*CF;           // 8
  int t = threadIdx.x;
  int q0 = bx*QB;

  if (t<8) sS[t]=0.f;
  for (int i=t; i<QB*CF; i+=256){
    int ql = i/CF, c = i&(CF-1);
    int qi = sel ? sel[b*Nq + q0 + ql] : (q0 + ql);
    fqs[i] = fk[((size_t)b*Nk + qi)*CF + c];
  }
  // stage weight half A (c < CF)
  for (int i=t; i<CF*COUT; i+=256){
    int o = i/CF, c = i&(CF-1);
    wtb[c*WS+o] = w[o*CIN + c];
  }
  if (t < QB*16){
    int ql = t>>4, k = t&15;
    int nid = knn[((size_t)b*Nq + q0 + ql)*16 + k];
    const float4* row = (const float4*)(fk + ((size_t)b*Nk + nid)*CF);
    float* ep = e + ql*ESTR + k;
    #pragma unroll
    for (int c4=0; c4<CF/4; ++c4){
      float4 v = row[c4];
      ep[(c4*4+0)*16]=v.x; ep[(c4*4+1)*16]=v.y; ep[(c4*4+2)*16]=v.z; ep[(c4*4+3)*16]=v.w;
    }
  }
  __syncthreads();

  int ql = t/GPQ, o = t%GPQ;
  const float* eb = e + ql*ESTR;
  const float* fqb = fqs + ql*CF;
  float y0[16], y1[16];
  #pragma unroll
  for (int k=0;k<16;++k){ y0[k]=0.f; y1[k]=0.f; }
  float zA0=0.f, zA1=0.f;
  for (int c=0;c<CF;++c){
    float w0 = wtb[c*WS+o];
    float w1 = wtb[c*WS+o+GPQ];
    float fqc = fqb[c];
    zA0 = fmaf(w0,fqc,zA0); zA1 = fmaf(w1,fqc,zA1);
    const float4* ev4 = (const float4*)(eb + c*16);
    #pragma unroll
    for (int k4=0;k4<4;++k4){
      float4 ev = ev4[k4];
      y0[k4*4+0]=fmaf(w0,ev.x,y0[k4*4+0]); y0[k4*4+1]=fmaf(w0,ev.y,y0[k4*4+1]);
      y0[k4*4+2]=fmaf(w0,ev.z,y0[k4*4+2]); y0[k4*4+3]=fmaf(w0,ev.w,y0[k4*4+3]);
      y1[k4*4+0]=fmaf(w1,ev.x,y1[k4*4+0]); y1[k4*4+1]=fmaf(w1,ev.y,y1[k4*4+1]);
      y1[k4*4+2]=fmaf(w1,ev.z,y1[k4*4+2]); y1[k4*4+3]=fmaf(w1,ev.w,y1[k4*4+3]);
    }
  }
  __syncthreads();
  // stage weight half B (c >= CF)
  for (int i=t; i<CF*COUT; i+=256){
    int oo = i/CF, c = i&(CF-1);
    wtb[c*WS+oo] = w[oo*CIN + CF + c];
  }
  __syncthreads();
  float zB0=0.f, zB1=0.f;
  for (int c=0;c<CF;++c){
    float fqc = fqb[c];
    zB0 = fmaf(wtb[c*WS+o],fqc,zB0);
    zB1 = fmaf(wtb[c*WS+o+GPQ],fqc,zB1);
  }
  float z0 = zB0 - zA0, z1 = zB1 - zA1;

  float mx0=-3.4e38f, mn0=3.4e38f, s0=0.f, q0s=0.f;
  float mx1=-3.4e38f, mn1=3.4e38f, s1=0.f, q1s=0.f;
  #pragma unroll
  for (int k=0;k<16;++k){
    float v0 = y0[k]+z0, v1 = y1[k]+z1;
    mx0=fmaxf(mx0,v0); mn0=fminf(mn0,v0); s0+=v0; q0s=fmaf(v0,v0,q0s);
    mx1=fmaxf(mx1,v1); mn1=fminf(mn1,v1); s1+=v1; q1s=fmaf(v1,v1,q1s);
  }
  int g0 = o/(COUT/4);
  atomicAdd(&sS[g0],   s0); atomicAdd(&sS[4+g0],   q0s);
  atomicAdd(&sS[g0+2], s1); atomicAdd(&sS[6+g0],   q1s);
  size_t mi0 = ((size_t)b*Nq + q0 + ql)*COUT + o;
  ((float2*)mm)[mi0]       = make_float2(mx0,mn0);
  ((float2*)mm)[mi0+GPQ]   = make_float2(mx1,mn1);
  __syncthreads();
  if (t<8){
    int g = t>>1, which = t&1;
    float val = which ? sS[4+g] : sS[g];
    atomicAdd(&stats[(((size_t)b*4+g)*8 + (bx&7))*2 + which], val);
  }
}

// ---------------------------------------------------------------------------
// Fused launches: FPS blocks first (grab CU slots immediately); independent
// knn/edge work fills the rest. Events are banned -> only overlap path.
__global__ __launch_bounds__(256,4) void fused1_kernel(
    const float* __restrict__ xyz0, int* __restrict__ knnb1,
    int* __restrict__ idx1, float* __restrict__ xyz1){
  __shared__ __align__(16) float smem[8752];   // fps1 needs 8752; knn 8320
  int bx = blockIdx.x;
  if (bx < 32){
    fps_body<2048,512>(smem, xyz0, idx1, xyz1, bx);
  } else {
    int rid = bx - 32;                          // 1024 knn1 blocks
    knn_body<2048,64>(smem, xyz0, xyz0, 2048, knnb1, rid & 31, rid >> 5);
  }
}

__global__ __launch_bounds__(256,4) void fused2_kernel(
    const float* __restrict__ xyz0, const float* __restrict__ xyz1,
    const int* __restrict__ knnb1,
    int* __restrict__ knnb2, int* __restrict__ knnb3,
    int* __restrict__ idx2, float* __restrict__ xyz2,
    const float* __restrict__ f0, const float* __restrict__ cw1,
    float* __restrict__ mmb, float* __restrict__ stats1){
  __shared__ __align__(16) float smem[8320];   // knn 8320 > edge1 2576 > fps2 2224
  int bx = blockIdx.x;
  if (bx < 32){
    fps_body<512,128>(smem, xyz1, idx2, xyz2, bx);
  } else if (bx < 288){
    int rid = bx - 32;                          // 256 knn2 blocks
    knn_body<2048,64>(smem, xyz1, xyz0, 512, knnb2, rid & 7, rid >> 3);
  } else if (bx < 544){
    int rid = bx - 288;                         // 256 knn3 blocks
    knn_body<512,64>(smem, xyz1, xyz1, 512, knnb3, rid & 7, rid >> 3);
  } else {
    int rid = bx - 544;                         // 4096 edge1 blocks
    edge_body<8,32,16>(smem, f0, nullptr, knnb1, cw1, mmb, stats1,
                       2048, 2048, rid & 127, rid >> 7);
  }
}

// fused3: knn4 (64 blocks; needs xyz2/xyz1, ready after fused2) || edge2
// (2048 blocks; needs f1 from fin1 and knnb2 from fused2). Launched after
// fin1 -> all dependencies satisfied; removes the standalone knn4 launch.
__global__ __launch_bounds__(256,4) void fused3_kernel(
    const float* __restrict__ xyz1, const float* __restrict__ xyz2,
    int* __restrict__ knnb4,
    const float* __restrict__ f1, const int* __restrict__ idx1,
    const int* __restrict__ knnb2, const float* __restrict__ cw2,
    float* __restrict__ mmb, float* __restrict__ stats2){
  __shared__ __align__(16) float smem[8320];   // knn 8320 > edge2 6504
  int bx = blockIdx.x;
  if (bx < 64){
    knn_body<512,64>(smem, xyz2, xyz1, 128, knnb4, bx & 1, bx >> 1);
  } else {
    int rid = bx - 64;                          // 2048 edge2 blocks
    edge_body<32,64,8>(smem, f1, idx1, knnb2, cw2, mmb, stats2,
                       512, 2048, rid & 63, rid >> 6);
  }
}

template<int CF,int COUT,int QB>
__global__ __launch_bounds__(256) void edge_kernel(
    const float* __restrict__ fk, const int* __restrict__ sel,
    const int* __restrict__ knn, const float* __restrict__ w,
    float* __restrict__ mm, float* __restrict__ stats, int Nq, int Nk){
  constexpr int WS  = COUT+1;
  constexpr int ESTR= CF*16+8;
  constexpr int WTB = ((CF*WS+3)&~3);
  constexpr int SM  = WTB + QB*ESTR + QB*CF + 8;
  __shared__ __align__(16) float smem[SM];
  edge_body<CF,COUT,QB>(smem, fk, sel, knn, w, mm, stats, Nq, Nk,
                        blockIdx.x, blockIdx.y);
}

// ---------------------------------------------------------------------------
// finalize: sum stat buckets, GN affine on max (min if a<0) + LeakyReLU.
__global__ __launch_bounds__(256) void fin_kernel(
    const float* __restrict__ mm, const float* __restrict__ stats,
    const float* __restrict__ gam, const float* __restrict__ bet,
    float* __restrict__ fo, void* __restrict__ outbase, const int* __restrict__ flag,
    int outoff, int Nq, int COUT, float invcnt, int total){
  for (int i = blockIdx.x*256 + threadIdx.x; i<total; i += gridDim.x*256){
    int o = i % COUT;
    int r = i / COUT;
    int q = r % Nq;
    int b = r / Nq;
    int g = o / (COUT>>2);
    const float* sp = stats + ((size_t)(b*4+g))*16;
    float s=0.f, s2=0.f;
    #pragma unroll
    for (int nb=0;nb<8;++nb){ s += sp[nb*2]; s2 += sp[nb*2+1]; }
    float mean = s*invcnt;
    float var  = fmaxf(s2*invcnt - mean*mean, 0.f);
    float inv  = 1.0f / sqrtf(var + 1e-5f);
    float a  = gam[o] * inv;
    float bb = bet[o] - a*mean;
    const float* mp = mm + (size_t)i*2;
    float xv = (a>=0.f) ? mp[0] : mp[1];  // monotone affine: max commutes
    float v = fmaf(a, xv, bb);
    v = (v>=0.f) ? v : 0.2f*v;
    if (fo) fo[i]=v;
    if (outbase){
      int idx = outoff + ((b*COUT + o)*Nq + q);
      if (*flag) ((float*)outbase)[idx] = v;
      else       ((unsigned short*)outbase)[idx] = f2bf(v);
    }
  }
}

__global__ __launch_bounds__(256) void coor_kernel(
    const float* __restrict__ xyz2, void* __restrict__ outbase,
    const int* __restrict__ flag){
  int i = blockIdx.x*256+threadIdx.x;   // 32*3*128
  int m = i & 127;
  int c = (i>>7) % 3;
  int b = i / 384;
  float v = xyz2[((size_t)b*128+m)*3 + c];
  if (*flag) ((float*)outbase)[i] = v;
  else       ((unsigned short*)outbase)[i] = f2bf(v);
}

// ---------------------------------------------------------------------------
extern "C" void kernel_launch(void* const* d_in, const int* in_sizes, int n_in,
                              void* d_out, int out_size, void* d_ws, size_t ws_size,
                              hipStream_t stream){
  float* W    = (float*)d_ws;
  float* xyz0 = W;                      // 196608
  float* f0   = W + 196608;             // 524288
  float* f1   = W + 720896;             // 2097152
  float* xyz1 = W + 2818048;            // 49152
  float* f2   = W + 2867200;            // 1048576
  float* f3   = W + 3915776;            // 1048576
  float* xyz2 = W + 4964352;            // 12288
  float* stats= W + 4976640;            // 8192 (4 layers x 32 x 4 x 8buckets x 2)
  int*   flag = (int*)(W + 4984832);    // 16 (pad)
  float* PRM  = W + 4984848;            // 29792 canonical fp32 params
  int*  idx1  = (int*)(W + 5014640);    // 16384
  int*  idx2  = (int*)(W + 5031024);    // 4096
  float* SCR  = W + 5035120;            // aliased per-layer scratch
  int*   knnb = (int*)SCR;              // knn1: 1048576 ints (dead after fused2)
  int*   knnb4= (int*)SCR;              // knn4 reuses knn1 region (65536 ints)
  int*   knnb2= (int*)f3;               // knn2: 262144 ints in f3 (dead at fin3)
  int*   knnb3= (int*)f3 + 262144;      // knn3: 262144 ints in f3
  float* mmb  = SCR + 1048576;          // <= 4194304 floats
  // total ~ 41.1 MB (unchanged)

  float* cw_in = PRM;          // 24
  float* cb_in = PRM+24;       // 8
  float* cw1 = PRM+32;   float* cg1 = PRM+544;   float* cbb1 = PRM+576;   // 512,32,32
  float* cw2 = PRM+608;  float* cg2 = PRM+4704;  float* cbb2 = PRM+4768;  // 4096,64,64
  float* cw3 = PRM+4832; float* cg3 = PRM+13024; float* cbb3 = PRM+13088; // 8192,64,64
  float* cw4 = PRM+13152;float* cg4 = PRM+29536; float* cbb4 = PRM+29664; // 16384,128,128

  detect_kernel<<<1,256,0,stream>>>((const unsigned short*)d_in[0], flag);

  PConv pc;
  const int psz[14] = {24,8,512,32,32,4096,64,64,8192,64,64,16384,128,128};
  float* pdst[14] = {cw_in,cb_in,cw1,cg1,cbb1,cw2,cg2,cbb2,cw3,cg3,cbb3,cw4,cg4,cbb4};
  for (int j=0;j<14;++j){ pc.s[j]=d_in[j+1]; pc.d[j]=pdst[j]; pc.sz[j]=psz[j]; }
  conv_params_kernel<<<117,256,0,stream>>>(pc, flag);

  prep_kernel<<<256,256,0,stream>>>(d_in[0], flag, cw_in, cb_in, xyz0, f0, stats);

  // ---- fused1: FPS 2048->512 (32 blocks) || knn1 (1024 blocks)
  fused1_kernel<<<1056,256,0,stream>>>(xyz0, knnb, idx1, xyz1);

  // ---- fused2: FPS 512->128 (32) || knn2 (256) || knn3 (256) || edge1 (4096)
  fused2_kernel<<<4640,256,0,stream>>>(xyz0, xyz1, knnb, knnb2, knnb3,
                                       idx2, xyz2, f0, cw1, mmb, stats+0);

  // ---- layer 1 finalize
  fin_kernel<<<1024,256,0,stream>>>(mmb, stats+0, cg1, cbb1, f1, nullptr, flag, 0, 2048, 32, 1.f/262144.f, 2097152);

  // ---- fused3: knn4 (64 blocks) || edge2 (2048 blocks)
  fused3_kernel<<<2112,256,0,stream>>>(xyz1, xyz2, knnb4,
                                       f1, idx1, knnb2, cw2, mmb, stats+2048);
  fin_kernel<<<1024,256,0,stream>>>(mmb, stats+2048, cg2, cbb2, f2, nullptr, flag, 0, 512, 64, 1.f/131072.f, 1048576);

  // ---- layer 3: 512q/512k, 128 -> 64
  edge_kernel<64,64,8><<<dim3(64,32),256,0,stream>>>(f2, nullptr, knnb3, cw3, mmb, stats+4096, 512, 512);
  fin_kernel<<<1024,256,0,stream>>>(mmb, stats+4096, cg3, cbb3, f3, nullptr, flag, 0, 512, 64, 1.f/131072.f, 1048576);

  // ---- layer 4: 128q/512k, 128 -> 128 (queries via idx2) -> final f output
  edge_kernel<64,128,4><<<dim3(32,32),256,0,stream>>>(f3, idx2, knnb4, cw4, mmb, stats+6144, 128, 512);
  fin_kernel<<<1024,256,0,stream>>>(mmb, stats+6144, cg4, cbb4, nullptr, d_out, flag, 12288, 128, 128, 1.f/65536.f, 524288);

  // ---- coor output (B,3,128)
  coor_kernel<<<48,256,0,stream>>>(xyz2, d_out, flag);
}

// Round 12
// 762.804 us; speedup vs baseline: 4.7244x; 1.0050x over previous
//
#include <hip/hip_runtime.h>
#include <hip/hip_bf16.h>

#define DEV __device__ __forceinline__

DEV float bf2f(unsigned short u){ return __uint_as_float(((unsigned)u)<<16); }
DEV unsigned short f2bf(float f){
  unsigned u = __float_as_uint(f);
  u += 0x7fffu + ((u>>16)&1u);   // RNE
  return (unsigned short)(u>>16);
}

// DPP-based u64 max step: permute both halves identically, umax with self as
// fallback (identity). ctrl: 0x110|N=row_shr:N, 0x142=row_bcast15, 0x143=row_bcast31.
template<int CTRL>
DEV unsigned long long dpp_umax(unsigned long long k){
  int lo = (int)(unsigned)k;
  int hi = (int)(unsigned)(k>>32);
  int plo = __builtin_amdgcn_update_dpp(lo, lo, CTRL, 0xF, 0xF, false);
  int phi = __builtin_amdgcn_update_dpp(hi, hi, CTRL, 0xF, 0xF, false);
  unsigned long long p = ((unsigned long long)(unsigned)phi << 32) | (unsigned)plo;
  return (p > k) ? p : k;
}

// ---------------------------------------------------------------------------
// dtype detection: genuine bf16 N(0,1) data never has exponent >= 0xC0;
// fp32 read as ushorts has ~25% such halfwords. flag=1 -> inputs fp32.
__global__ __launch_bounds__(256) void detect_kernel(
    const unsigned short* __restrict__ x, int* __restrict__ flag){
  __shared__ int cnt;
  if (threadIdx.x==0) cnt = 0;
  __syncthreads();
  int local = 0;
  for (int i=threadIdx.x; i<4096; i+=256){
    int e = (x[i]>>7)&0xFF;
    if (e >= 0xC0) local++;
  }
  atomicAdd(&cnt, local);
  __syncthreads();
  if (threadIdx.x==0) *flag = (cnt > 64) ? 1 : 0;
}

// ---------------------------------------------------------------------------
struct PConv {
  const void* s[14];
  float*      d[14];
  int         sz[14];
};

// prep (merged): blocks 0..116 canonicalize the 14 param tensors to fp32;
// blocks 117..372 do coord transpose + f0 embed + stats zero. The prep path
// converts w_in/b_in inline from the raw inputs (no dependency on the conv
// blocks -> safe to run in one kernel).
__global__ __launch_bounds__(256) void prep_kernel(
    const void* __restrict__ xraw, const int* __restrict__ flag,
    const void* __restrict__ w_in_raw, const void* __restrict__ b_in_raw,
    PConv p,
    float* __restrict__ xyz0, float* __restrict__ f0, float* __restrict__ stats){
  bool isf = (*flag != 0);
  int bx = blockIdx.x;
  if (bx < 117){
    int i = bx*256 + threadIdx.x;
    int seg = 0, off = i;
    #pragma unroll
    for (seg=0; seg<14; ++seg){
      if (off < p.sz[seg]) break;
      off -= p.sz[seg];
    }
    if (seg >= 14) return;
    float v = isf ? ((const float*)p.s[seg])[off]
                  : bf2f(((const unsigned short*)p.s[seg])[off]);
    p.d[seg][off] = v;
    return;
  }
  int i = (bx-117)*256 + threadIdx.x;            // 32*2048 threads
  if (i < 8192) stats[i] = 0.f;
  int b = i >> 11, n = i & 2047;
  size_t base = (size_t)b*3*2048 + n;
  float X, Y, Z;
  if (isf){
    const float* xf = (const float*)xraw;
    X = xf[base]; Y = xf[base+2048]; Z = xf[base+4096];
  } else {
    const unsigned short* xu = (const unsigned short*)xraw;
    X = bf2f(xu[base]); Y = bf2f(xu[base+2048]); Z = bf2f(xu[base+4096]);
  }
  float* o3 = xyz0 + (size_t)i*3;
  o3[0]=X; o3[1]=Y; o3[2]=Z;
  const float* wf = (const float*)w_in_raw;
  const float* bf = (const float*)b_in_raw;
  const unsigned short* wu = (const unsigned short*)w_in_raw;
  const unsigned short* bu = (const unsigned short*)b_in_raw;
  float* fo = f0 + (size_t)i*8;
  #pragma unroll
  for (int o=0;o<8;++o){
    float w0 = isf ? wf[o*3+0] : bf2f(wu[o*3+0]);
    float w1 = isf ? wf[o*3+1] : bf2f(wu[o*3+1]);
    float w2 = isf ? wf[o*3+2] : bf2f(wu[o*3+2]);
    float bb = isf ? bf[o]     : bf2f(bu[o]);
    fo[o] = w0*X + w1*Y + w2*Z + bb;
  }
}

// ---------------------------------------------------------------------------
// Split-K kNN body (256 threads): 4 threads/query, thread h scans m==h (mod 4),
// private sorted top-16 (strict-< insert => stable), leader 4-way lex merge.
// smem: >= max(NK*4, 130*QB) floats.
template<int NK, int QB>
DEV void knn_body(float* smem, const float* __restrict__ qxyz,
                  const float* __restrict__ kxyz, int Nq,
                  int* __restrict__ oidx, int bx, int b){
  float4* kd = (float4*)smem;
  int t = threadIdx.x;
  for (int i=t; i<NK; i+=256){
    const float* p = kxyz + ((size_t)b*NK + i)*3;
    float X=p[0], Y=p[1], Z=p[2];
    float sk = __fadd_rn(__fadd_rn(__fmul_rn(X,X),__fmul_rn(Y,Y)),__fmul_rn(Z,Z));
    kd[i] = make_float4(X,Y,Z,sk);
  }
  __syncthreads();
  int ql = t>>2, h = t&3;
  int q0 = bx*QB;
  const float* qp = qxyz + ((size_t)b*Nq + q0 + ql)*3;
  float QX=qp[0], QY=qp[1], QZ=qp[2];
  float sq = __fadd_rn(__fadd_rn(__fmul_rn(QX,QX),__fmul_rn(QY,QY)),__fmul_rn(QZ,QZ));
  float dl[16]; int il[16];
  #pragma unroll
  for (int j=0;j<16;++j){ dl[j]=3.4e38f; il[j]=-1; }
  for (int i=0; i<NK/4; i+=8){
    float d[8];
    #pragma unroll
    for (int u=0;u<8;++u){
      float4 c = kd[4*(i+u)+h];
      float dot = __fadd_rn(__fadd_rn(__fmul_rn(QX,c.x),__fmul_rn(QY,c.y)),__fmul_rn(QZ,c.z));
      d[u] = __fsub_rn(__fadd_rn(sq, c.w), __fmul_rn(2.0f,dot));
    }
    float dmin = fminf(fminf(fminf(d[0],d[1]),fminf(d[2],d[3])),
                       fminf(fminf(d[4],d[5]),fminf(d[6],d[7])));
    if (dmin < dl[15]){
      #pragma unroll
      for (int u=0;u<8;++u){
        float du = d[u];
        if (du < dl[15]){               // strict <: equal dist keeps earlier index
          dl[15]=du; il[15]=4*(i+u)+h;
          #pragma unroll
          for (int s=15;s>0;--s){
            if (dl[s] < dl[s-1]){       // strict <: stable among equals
              float td=dl[s]; dl[s]=dl[s-1]; dl[s-1]=td;
              int   ti=il[s]; il[s]=il[s-1]; il[s-1]=ti;
            }
          }
        }
      }
    }
  }
  __syncthreads();                       // kd reads done; reuse smem for lists
  float* dbuf = smem;
  int*   ibuf = (int*)(smem + QB*65);
  int base = ql*65 + h*16;
  #pragma unroll
  for (int j=0;j<16;++j){ dbuf[base+j]=dl[j]; ibuf[base+j]=il[j]; }
  __syncthreads();
  if (t < QB){
    const float* db = dbuf + t*65;
    const int*   ib = ibuf + t*65;
    int p0=0,p1=0,p2=0,p3=0;
    int* op = oidx + ((size_t)b*Nq + q0 + t)*16;
    #pragma unroll 1
    for (int j=0;j<16;++j){
      float e0 = (p0<16)? db[p0]    : 3.5e38f; int i0 = (p0<16)? ib[p0]    : 0x7fffffff;
      float e1 = (p1<16)? db[16+p1] : 3.5e38f; int i1 = (p1<16)? ib[16+p1] : 0x7fffffff;
      float e2 = (p2<16)? db[32+p2] : 3.5e38f; int i2 = (p2<16)? ib[32+p2] : 0x7fffffff;
      float e3 = (p3<16)? db[48+p3] : 3.5e38f; int i3 = (p3<16)? ib[48+p3] : 0x7fffffff;
      float bd=e0; int bi=i0; int bh=0;
      if (e1<bd || (e1==bd && i1<bi)){ bd=e1; bi=i1; bh=1; }
      if (e2<bd || (e2==bd && i2<bi)){ bd=e2; bi=i2; bh=2; }
      if (e3<bd || (e3==bd && i3<bi)){ bd=e3; bi=i3; bh=3; }
      op[j]=bi;
      p0 += (bh==0); p1 += (bh==1); p2 += (bh==2); p3 += (bh==3);
    }
  }
  __syncthreads();                       // safe smem handoff (fused callers)
}

// ---------------------------------------------------------------------------
// FPS body (256 threads, 4 waves, one barrier per step) — round-9 structure
// + s_setprio(3): fps waves win SIMD issue arbitration over co-resident knn
// waves (round-11 analysis: issue-slot contention, not the reduce, dominates
// the step). Packed u64 argmax key (fbits(dist)<<32)|(~idx): umax == lex
// (dist desc, idx asc) == ref tie-break. DPP chain to lane 63 + readlane;
// winner coords carried through the scan; parity double-buffered LDS slots.
// smem: NP*4 + 48 + G floats. Exact fp32 no-FMA math.
template<int NP,int G>
DEV void fps_body(float* smem, const float* __restrict__ xyz,
                  int* __restrict__ oidx, float* __restrict__ oxyz, int b){
  constexpr int PPT = NP/256;
  __builtin_amdgcn_s_setprio(3);
  float4* xl4 = (float4*)smem;
  unsigned long long* candK = (unsigned long long*)(smem + NP*4);   // [8] (2 par x 4 waves)
  float4* candX = (float4*)(smem + NP*4 + 16);                      // [8]
  int* selidx = (int*)(smem + NP*4 + 48);                           // [G]
  int t = threadIdx.x, w = t>>6;
  float px[PPT], py[PPT], pz[PPT], dist[PPT];
  #pragma unroll
  for (int j=0;j<PPT;++j){
    int gi = t + j*256;
    const float* p = xyz + ((size_t)b*NP + gi)*3;
    float X=p[0], Y=p[1], Z=p[2];
    px[j]=X; py[j]=Y; pz[j]=Z; dist[j]=1e10f;
    xl4[gi] = make_float4(X,Y,Z,0.f);
  }
  if (t==0) selidx[0] = 0;
  __syncthreads();
  float4 c0 = xl4[0];
  float cx=c0.x, cy=c0.y, cz=c0.z;
  int Bi = 0;
  for (int g=1; g<G; ++g){
    float bv=-1.f; int bi=0; float bxc=0.f, byc=0.f, bzc=0.f;
    #pragma unroll
    for (int j=0;j<PPT;++j){
      float dx=__fsub_rn(px[j],cx), dy=__fsub_rn(py[j],cy), dz=__fsub_rn(pz[j],cz);
      float d = __fadd_rn(__fadd_rn(__fmul_rn(dx,dx),__fmul_rn(dy,dy)),__fmul_rn(dz,dz));
      float nd = fminf(dist[j], d);
      dist[j] = nd;
      bool cc = (nd > bv);               // ascending idx in-lane: first-max kept
      bv = cc ? nd : bv;
      bi = cc ? (t + j*256) : bi;
      bxc = cc ? px[j] : bxc; byc = cc ? py[j] : byc; bzc = cc ? pz[j] : bzc;
    }
    unsigned long long klocal =
        ((unsigned long long)__float_as_uint(bv) << 32) | (unsigned)(0xFFFFFFFFu - bi);
    unsigned long long k = klocal;
    k = dpp_umax<0x111>(k);              // row_shr:1
    k = dpp_umax<0x112>(k);              // row_shr:2
    k = dpp_umax<0x114>(k);              // row_shr:4
    k = dpp_umax<0x118>(k);              // row_shr:8
    k = dpp_umax<0x142>(k);              // row_bcast15
    k = dpp_umax<0x143>(k);              // row_bcast31 -> lane 63 has wave max
    unsigned klo = (unsigned)__builtin_amdgcn_readlane((int)(unsigned)k, 63);
    unsigned khi = (unsigned)__builtin_amdgcn_readlane((int)(unsigned)(k>>32), 63);
    unsigned long long wkey = ((unsigned long long)khi<<32) | klo;
    int par = g & 1;
    if (klocal == wkey){                 // exactly one lane per wave (idx in key)
      candK[par*4 + w] = wkey;
      candX[par*4 + w] = make_float4(bxc, byc, bzc, 0.f);
    }
    __syncthreads();
    unsigned long long kk = candK[par*4+0]; float4 xx = candX[par*4+0];
    unsigned long long k1 = candK[par*4+1]; float4 x1 = candX[par*4+1];
    if (k1 > kk){ kk=k1; xx=x1; }
    unsigned long long k2 = candK[par*4+2]; float4 x2 = candX[par*4+2];
    if (k2 > kk){ kk=k2; xx=x2; }
    unsigned long long k3 = candK[par*4+3]; float4 x3 = candX[par*4+3];
    if (k3 > kk){ kk=k3; xx=x3; }
    Bi = (int)(0xFFFFFFFFu - (unsigned)kk);
    cx = xx.x; cy = xx.y; cz = xx.z;
    if (t==0) selidx[g] = Bi;
  }
  __syncthreads();
  for (int i=t; i<G; i+=256){
    int s = selidx[i];
    float4 c = xl4[s];
    oidx[(size_t)b*G + i] = s;
    float* op = oxyz + ((size_t)b*G + i)*3;
    op[0]=c.x; op[1]=c.y; op[2]=c.z;
  }
}

// ---------------------------------------------------------------------------
// EdgeConv pre-norm body (256 threads). See round-3 notes; smem-pointer form
// so it can run inside fused kernels. smem floats: WTB + QB*ESTR + QB*CF + 8.
template<int CF,int COUT,int QB>
DEV void edge_body(float* smem, const float* __restrict__ fk,
                   const int* __restrict__ sel, const int* __restrict__ knn,
                   const float* __restrict__ w, float* __restrict__ mm,
                   float* __restrict__ stats, int Nq, int Nk, int bx, int b){
  constexpr int CIN = 2*CF;
  constexpr int GPQ = COUT/2;
  constexpr int WS  = COUT+1;
  constexpr int ESTR= CF*16+8;
  constexpr int WTB = ((CF*WS+3)&~3);
  static_assert(QB*GPQ == 256, "block mapping");
  float* wtb = smem;                  // CF*WS
  float* e   = smem + WTB;            // QB*ESTR (16B aligned)
  float* fqs = e + QB*ESTR;           // QB*CF
  float* sS  = fqs + QB*CF;           // 8
  int t = threadIdx.x;
  int q0 = bx*QB;

  if (t<8) sS[t]=0.f;
  for (int i=t; i<QB*CF; i+=256){
    int ql = i/CF, c = i&(CF-1);
    int qi = sel ? sel[b*Nq + q0 + ql] : (q0 + ql);
    fqs[i] = fk[((size_t)b*Nk + qi)*CF + c];
  }
  // stage weight half A (c < CF)
  for (int i=t; i<CF*COUT; i+=256){
    int o = i/CF, c = i&(CF-1);
    wtb[c*WS+o] = w[o*CIN + c];
  }
  if (t < QB*16){
    int ql = t>>4, k = t&15;
    int nid = knn[((size_t)b*Nq + q0 + ql)*16 + k];
    const float4* row = (const float4*)(fk + ((size_t)b*Nk + nid)*CF);
    float* ep = e + ql*ESTR + k;
    #pragma unroll
    for (int c4=0; c4<CF/4; ++c4){
      float4 v = row[c4];
      ep[(c4*4+0)*16]=v.x; ep[(c4*4+1)*16]=v.y; ep[(c4*4+2)*16]=v.z; ep[(c4*4+3)*16]=v.w;
    }
  }
  __syncthreads();

  int ql = t/GPQ, o = t%GPQ;
  const float* eb = e + ql*ESTR;
  const float* fqb = fqs + ql*CF;
  float y0[16], y1[16];
  #pragma unroll
  for (int k=0;k<16;++k){ y0[k]=0.f; y1[k]=0.f; }
  float zA0=0.f, zA1=0.f;
  for (int c=0;c<CF;++c){
    float w0 = wtb[c*WS+o];
    float w1 = wtb[c*WS+o+GPQ];
    float fqc = fqb[c];
    zA0 = fmaf(w0,fqc,zA0); zA1 = fmaf(w1,fqc,zA1);
    const float4* ev4 = (const float4*)(eb + c*16);
    #pragma unroll
    for (int k4=0;k4<4;++k4){
      float4 ev = ev4[k4];
      y0[k4*4+0]=fmaf(w0,ev.x,y0[k4*4+0]); y0[k4*4+1]=fmaf(w0,ev.y,y0[k4*4+1]);
      y0[k4*4+2]=fmaf(w0,ev.z,y0[k4*4+2]); y0[k4*4+3]=fmaf(w0,ev.w,y0[k4*4+3]);
      y1[k4*4+0]=fmaf(w1,ev.x,y1[k4*4+0]); y1[k4*4+1]=fmaf(w1,ev.y,y1[k4*4+1]);
      y1[k4*4+2]=fmaf(w1,ev.z,y1[k4*4+2]); y1[k4*4+3]=fmaf(w1,ev.w,y1[k4*4+3]);
    }
  }
  __syncthreads();
  // stage weight half B (c >= CF)
  for (int i=t; i<CF*COUT; i+=256){
    int oo = i/CF, c = i&(CF-1);
    wtb[c*WS+oo] = w[oo*CIN + CF + c];
  }
  __syncthreads();
  float zB0=0.f, zB1=0.f;
  for (int c=0;c<CF;++c){
    float fqc = fqb[c];
    zB0 = fmaf(wtb[c*WS+o],fqc,zB0);
    zB1 = fmaf(wtb[c*WS+o+GPQ],fqc,zB1);
  }
  float z0 = zB0 - zA0, z1 = zB1 - zA1;

  float mx0=-3.4e38f, mn0=3.4e38f, s0=0.f, q0s=0.f;
  float mx1=-3.4e38f, mn1=3.4e38f, s1=0.f, q1s=0.f;
  #pragma unroll
  for (int k=0;k<16;++k){
    float v0 = y0[k]+z0, v1 = y1[k]+z1;
    mx0=fmaxf(mx0,v0); mn0=fminf(mn0,v0); s0+=v0; q0s=fmaf(v0,v0,q0s);
    mx1=fmaxf(mx1,v1); mn1=fminf(mn1,v1); s1+=v1; q1s=fmaf(v1,v1,q1s);
  }
  int g0 = o/(COUT/4);
  atomicAdd(&sS[g0],   s0); atomicAdd(&sS[4+g0],   q0s);
  atomicAdd(&sS[g0+2], s1); atomicAdd(&sS[6+g0],   q1s);
  size_t mi0 = ((size_t)b*Nq + q0 + ql)*COUT + o;
  ((float2*)mm)[mi0]       = make_float2(mx0,mn0);
  ((float2*)mm)[mi0+GPQ]   = make_float2(mx1,mn1);
  __syncthreads();
  if (t<8){
    int g = t>>1, which = t&1;
    float val = which ? sS[4+g] : sS[g];
    atomicAdd(&stats[(((size_t)b*4+g)*8 + (bx&7))*2 + which], val);
  }
}

// ---------------------------------------------------------------------------
// Fused launches: FPS blocks first (grab CU slots immediately); independent
// knn/edge work fills the rest. Events are banned -> only overlap path.
__global__ __launch_bounds__(256,4) void fused1_kernel(
    const float* __restrict__ xyz0, int* __restrict__ knnb1,
    int* __restrict__ idx1, float* __restrict__ xyz1){
  __shared__ __align__(16) float smem[8752];   // fps1 needs 8752; knn 8320
  int bx = blockIdx.x;
  if (bx < 32){
    fps_body<2048,512>(smem, xyz0, idx1, xyz1, bx);
  } else {
    int rid = bx - 32;                          // 1024 knn1 blocks
    knn_body<2048,64>(smem, xyz0, xyz0, 2048, knnb1, rid & 31, rid >> 5);
  }
}

__global__ __launch_bounds__(256,4) void fused2_kernel(
    const float* __restrict__ xyz0, const float* __restrict__ xyz1,
    const int* __restrict__ knnb1,
    int* __restrict__ knnb2, int* __restrict__ knnb3,
    int* __restrict__ idx2, float* __restrict__ xyz2,
    const float* __restrict__ f0, const float* __restrict__ cw1,
    float* __restrict__ mmb, float* __restrict__ stats1){
  __shared__ __align__(16) float smem[8320];   // knn 8320 > edge1 2576 > fps2 2224
  int bx = blockIdx.x;
  if (bx < 32){
    fps_body<512,128>(smem, xyz1, idx2, xyz2, bx);
  } else if (bx < 288){
    int rid = bx - 32;                          // 256 knn2 blocks
    knn_body<2048,64>(smem, xyz1, xyz0, 512, knnb2, rid & 7, rid >> 3);
  } else if (bx < 544){
    int rid = bx - 288;                         // 256 knn3 blocks
    knn_body<512,64>(smem, xyz1, xyz1, 512, knnb3, rid & 7, rid >> 3);
  } else {
    int rid = bx - 544;                         // 4096 edge1 blocks
    edge_body<8,32,16>(smem, f0, nullptr, knnb1, cw1, mmb, stats1,
                       2048, 2048, rid & 127, rid >> 7);
  }
}

// fused3: knn4 (64 blocks; needs xyz2/xyz1, ready after fused2) || edge2
// (2048 blocks; needs f1 from fin1 and knnb2 from fused2). Launched after
// fin1 -> all dependencies satisfied; removes the standalone knn4 launch.
__global__ __launch_bounds__(256,4) void fused3_kernel(
    const float* __restrict__ xyz1, const float* __restrict__ xyz2,
    int* __restrict__ knnb4,
    const float* __restrict__ f1, const int* __restrict__ idx1,
    const int* __restrict__ knnb2, const float* __restrict__ cw2,
    float* __restrict__ mmb, float* __restrict__ stats2){
  __shared__ __align__(16) float smem[8320];   // knn 8320 > edge2 6504
  int bx = blockIdx.x;
  if (bx < 64){
    knn_body<512,64>(smem, xyz2, xyz1, 128, knnb4, bx & 1, bx >> 1);
  } else {
    int rid = bx - 64;                          // 2048 edge2 blocks
    edge_body<32,64,8>(smem, f1, idx1, knnb2, cw2, mmb, stats2,
                       512, 2048, rid & 63, rid >> 6);
  }
}

template<int CF,int COUT,int QB>
__global__ __launch_bounds__(256) void edge_kernel(
    const float* __restrict__ fk, const int* __restrict__ sel,
    const int* __restrict__ knn, const float* __restrict__ w,
    float* __restrict__ mm, float* __restrict__ stats, int Nq, int Nk){
  constexpr int WS  = COUT+1;
  constexpr int ESTR= CF*16+8;
  constexpr int WTB = ((CF*WS+3)&~3);
  constexpr int SM  = WTB + QB*ESTR + QB*CF + 8;
  __shared__ __align__(16) float smem[SM];
  edge_body<CF,COUT,QB>(smem, fk, sel, knn, w, mm, stats, Nq, Nk,
                        blockIdx.x, blockIdx.y);
}

// ---------------------------------------------------------------------------
// finalize: sum stat buckets, GN affine on max (min if a<0) + LeakyReLU.
__global__ __launch_bounds__(256) void fin_kernel(
    const float* __restrict__ mm, const float* __restrict__ stats,
    const float* __restrict__ gam, const float* __restrict__ bet,
    float* __restrict__ fo, void* __restrict__ outbase, const int* __restrict__ flag,
    int outoff, int Nq, int COUT, float invcnt, int total){
  for (int i = blockIdx.x*256 + threadIdx.x; i<total; i += gridDim.x*256){
    int o = i % COUT;
    int r = i / COUT;
    int q = r % Nq;
    int b = r / Nq;
    int g = o / (COUT>>2);
    const float* sp = stats + ((size_t)(b*4+g))*16;
    float s=0.f, s2=0.f;
    #pragma unroll
    for (int nb=0;nb<8;++nb){ s += sp[nb*2]; s2 += sp[nb*2+1]; }
    float mean = s*invcnt;
    float var  = fmaxf(s2*invcnt - mean*mean, 0.f);
    float inv  = 1.0f / sqrtf(var + 1e-5f);
    float a  = gam[o] * inv;
    float bb = bet[o] - a*mean;
    const float* mp = mm + (size_t)i*2;
    float xv = (a>=0.f) ? mp[0] : mp[1];  // monotone affine: max commutes
    float v = fmaf(a, xv, bb);
    v = (v>=0.f) ? v : 0.2f*v;
    if (fo) fo[i]=v;
    if (outbase){
      int idx = outoff + ((b*COUT + o)*Nq + q);
      if (*flag) ((float*)outbase)[idx] = v;
      else       ((unsigned short*)outbase)[idx] = f2bf(v);
    }
  }
}

__global__ __launch_bounds__(256) void coor_kernel(
    const float* __restrict__ xyz2, void* __restrict__ outbase,
    const int* __restrict__ flag){
  int i = blockIdx.x*256+threadIdx.x;   // 32*3*128
  int m = i & 127;
  int c = (i>>7) % 3;
  int b = i / 384;
  float v = xyz2[((size_t)b*128+m)*3 + c];
  if (*flag) ((float*)outbase)[i] = v;
  else       ((unsigned short*)outbase)[i] = f2bf(v);
}

// ---------------------------------------------------------------------------
extern "C" void kernel_launch(void* const* d_in, const int* in_sizes, int n_in,
                              void* d_out, int out_size, void* d_ws, size_t ws_size,
                              hipStream_t stream){
  float* W    = (float*)d_ws;
  float* xyz0 = W;                      // 196608
  float* f0   = W + 196608;             // 524288
  float* f1   = W + 720896;             // 2097152
  float* xyz1 = W + 2818048;            // 49152
  float* f2   = W + 2867200;            // 1048576
  float* f3   = W + 3915776;            // 1048576
  float* xyz2 = W + 4964352;            // 12288
  float* stats= W + 4976640;            // 8192 (4 layers x 32 x 4 x 8buckets x 2)
  int*   flag = (int*)(W + 4984832);    // 16 (pad)
  float* PRM  = W + 4984848;            // 29792 canonical fp32 params
  int*  idx1  = (int*)(W + 5014640);    // 16384
  int*  idx2  = (int*)(W + 5031024);    // 4096
  float* SCR  = W + 5035120;            // aliased per-layer scratch
  int*   knnb = (int*)SCR;              // knn1: 1048576 ints (dead after fused2)
  int*   knnb4= (int*)SCR;              // knn4 reuses knn1 region (65536 ints)
  int*   knnb2= (int*)f3;               // knn2: 262144 ints in f3 (dead at fin3)
  int*   knnb3= (int*)f3 + 262144;      // knn3: 262144 ints in f3
  float* mmb  = SCR + 1048576;          // <= 4194304 floats
  // total ~ 41.1 MB (unchanged)

  float* cw_in = PRM;          // 24
  float* cb_in = PRM+24;       // 8
  float* cw1 = PRM+32;   float* cg1 = PRM+544;   float* cbb1 = PRM+576;   // 512,32,32
  float* cw2 = PRM+608;  float* cg2 = PRM+4704;  float* cbb2 = PRM+4768;  // 4096,64,64
  float* cw3 = PRM+4832; float* cg3 = PRM+13024; float* cbb3 = PRM+13088; // 8192,64,64
  float* cw4 = PRM+13152;float* cg4 = PRM+29536; float* cbb4 = PRM+29664; // 16384,128,128

  detect_kernel<<<1,256,0,stream>>>((const unsigned short*)d_in[0], flag);

  PConv pc;
  const int psz[14] = {24,8,512,32,32,4096,64,64,8192,64,64,16384,128,128};
  float* pdst[14] = {cw_in,cb_in,cw1,cg1,cbb1,cw2,cg2,cbb2,cw3,cg3,cbb3,cw4,cg4,cbb4};
  for (int j=0;j<14;++j){ pc.s[j]=d_in[j+1]; pc.d[j]=pdst[j]; pc.sz[j]=psz[j]; }

  // prep (merged): blocks 0..116 param conversion, 117..372 coords/f0/stats
  prep_kernel<<<373,256,0,stream>>>(d_in[0], flag, d_in[1], d_in[2], pc,
                                    xyz0, f0, stats);

  // ---- fused1: FPS 2048->512 (32 blocks, prio 3) || knn1 (1024 blocks)
  fused1_kernel<<<1056,256,0,stream>>>(xyz0, knnb, idx1, xyz1);

  // ---- fused2: FPS 512->128 (32) || knn2 (256) || knn3 (256) || edge1 (4096)
  fused2_kernel<<<4640,256,0,stream>>>(xyz0, xyz1, knnb, knnb2, knnb3,
                                       idx2, xyz2, f0, cw1, mmb, stats+0);

  // ---- coor output (B,3,128): xyz2 ready; independent of everything below
  coor_kernel<<<48,256,0,stream>>>(xyz2, d_out, flag);

  // ---- layer 1 finalize
  fin_kernel<<<1024,256,0,stream>>>(mmb, stats+0, cg1, cbb1, f1, nullptr, flag, 0, 2048, 32, 1.f/262144.f, 2097152);

  // ---- fused3: knn4 (64 blocks) || edge2 (2048 blocks)
  fused3_kernel<<<2112,256,0,stream>>>(xyz1, xyz2, knnb4,
                                       f1, idx1, knnb2, cw2, mmb, stats+2048);
  fin_kernel<<<1024,256,0,stream>>>(mmb, stats+2048, cg2, cbb2, f2, nullptr, flag, 0, 512, 64, 1.f/131072.f, 1048576);

  // ---- layer 3: 512q/512k, 128 -> 64
  edge_kernel<64,64,8><<<dim3(64,32),256,0,stream>>>(f2, nullptr, knnb3, cw3, mmb, stats+4096, 512, 512);
  fin_kernel<<<1024,256,0,stream>>>(mmb, stats+4096, cg3, cbb3, f3, nullptr, flag, 0, 512, 64, 1.f/131072.f, 1048576);

  // ---- layer 4: 128q/512k, 128 -> 128 (queries via idx2) -> final f output
  edge_kernel<64,128,4><<<dim3(32,32),256,0,stream>>>(f3, idx2, knnb4, cw4, mmb, stats+6144, 128, 512);
  fin_kernel<<<1024,256,0,stream>>>(mmb, stats+6144, cg4, cbb4, nullptr, d_out, flag, 12288, 128, 128, 1.f/65536.f, 524288);
}

// Round 13
// 620.201 us; speedup vs baseline: 5.8107x; 1.2299x over previous
//
#include <hip/hip_runtime.h>
#include <hip/hip_bf16.h>

#define DEV __device__ __forceinline__
typedef unsigned long long u64;

DEV float bf2f(unsigned short u){ return __uint_as_float(((unsigned)u)<<16); }
DEV unsigned short f2bf(float f){
  unsigned u = __float_as_uint(f);
  u += 0x7fffu + ((u>>16)&1u);   // RNE
  return (unsigned short)(u>>16);
}

// DPP-based u64 max step (fps wave reduce).
template<int CTRL>
DEV u64 dpp_umax(u64 k){
  int lo = (int)(unsigned)k;
  int hi = (int)(unsigned)(k>>32);
  int plo = __builtin_amdgcn_update_dpp(lo, lo, CTRL, 0xF, 0xF, false);
  int phi = __builtin_amdgcn_update_dpp(hi, hi, CTRL, 0xF, 0xF, false);
  u64 p = ((u64)(unsigned)phi << 32) | (unsigned)plo;
  return (p > k) ? p : k;
}

// compare-exchange on u64 keys (asc)
DEV void ce64(u64 &a, u64 &b){
  u64 lo = (a<b)?a:b;
  u64 hi = (a<b)?b:a;
  a = lo; b = hi;
}
// bitonic sort-8 ascending (textbook network, compile-time unrolled)
DEV void sort8(u64* x){
  #pragma unroll
  for (int k=2;k<=8;k<<=1){
    #pragma unroll
    for (int j=k>>1;j>0;j>>=1){
      #pragma unroll
      for (int i=0;i<8;++i){
        int l = i^j;
        if (l>i){
          if ((i&k)==0) ce64(x[i],x[l]);
          else          ce64(x[l],x[i]);
        }
      }
    }
  }
}
// bitonic merge: sort a bitonic 16-sequence ascending (32 CEs)
DEV void bm16(u64* A){
  #pragma unroll
  for (int gap=8;gap>0;gap>>=1){
    #pragma unroll
    for (int i=0;i<16;++i){
      if ((i&gap)==0) ce64(A[i], A[i|gap]);
    }
  }
}
// float -> order-preserving u32 (handles negative-epsilon dists exactly)
DEV unsigned f2sort(float d){
  unsigned ub = __float_as_uint(d);
  unsigned s  = (unsigned)((int)ub >> 31);
  return ub ^ (s | 0x80000000u);
}

// ---------------------------------------------------------------------------
struct PConv {
  const void* s[14];
  float*      d[14];
  int         sz[14];
};

// prep (merged): every block locally detects dtype (bf16 N(0,1) never has
// exponent >= 0xC0; fp32-as-ushort does ~25% of the time); block 0 publishes
// the flag for downstream fin/coor. Blocks 0..116 canonicalize the 14 param
// tensors; blocks 117..372 do coord transpose + f0 embed + stats zero.
__global__ __launch_bounds__(256) void prep_kernel(
    const void* __restrict__ xraw, int* __restrict__ flagw,
    const void* __restrict__ w_in_raw, const void* __restrict__ b_in_raw,
    PConv p,
    float* __restrict__ xyz0, float* __restrict__ f0, float* __restrict__ stats){
  __shared__ int cnt;
  int t = threadIdx.x;
  if (t==0) cnt = 0;
  __syncthreads();
  {
    const unsigned short* xs = (const unsigned short*)xraw;
    int local = 0;
    for (int i=t; i<4096; i+=256){
      int e = (xs[i]>>7)&0xFF;
      if (e >= 0xC0) local++;
    }
    atomicAdd(&cnt, local);
  }
  __syncthreads();
  bool isf = (cnt > 64);
  int bx = blockIdx.x;
  if (bx==0 && t==0) *flagw = isf ? 1 : 0;
  if (bx < 117){
    int i = bx*256 + t;
    int seg = 0, off = i;
    #pragma unroll
    for (seg=0; seg<14; ++seg){
      if (off < p.sz[seg]) break;
      off -= p.sz[seg];
    }
    if (seg >= 14) return;
    float v = isf ? ((const float*)p.s[seg])[off]
                  : bf2f(((const unsigned short*)p.s[seg])[off]);
    p.d[seg][off] = v;
    return;
  }
  int i = (bx-117)*256 + t;                      // 32*2048 threads
  if (i < 8192) stats[i] = 0.f;
  int b = i >> 11, n = i & 2047;
  size_t base = (size_t)b*3*2048 + n;
  float X, Y, Z;
  if (isf){
    const float* xf = (const float*)xraw;
    X = xf[base]; Y = xf[base+2048]; Z = xf[base+4096];
  } else {
    const unsigned short* xu = (const unsigned short*)xraw;
    X = bf2f(xu[base]); Y = bf2f(xu[base+2048]); Z = bf2f(xu[base+4096]);
  }
  float* o3 = xyz0 + (size_t)i*3;
  o3[0]=X; o3[1]=Y; o3[2]=Z;
  const float* wf = (const float*)w_in_raw;
  const float* bf = (const float*)b_in_raw;
  const unsigned short* wu = (const unsigned short*)w_in_raw;
  const unsigned short* bu = (const unsigned short*)b_in_raw;
  float* fo = f0 + (size_t)i*8;
  #pragma unroll
  for (int o=0;o<8;++o){
    float w0 = isf ? wf[o*3+0] : bf2f(wu[o*3+0]);
    float w1 = isf ? wf[o*3+1] : bf2f(wu[o*3+1]);
    float w2 = isf ? wf[o*3+2] : bf2f(wu[o*3+2]);
    float bb = isf ? bf[o]     : bf2f(bu[o]);
    fo[o] = w0*X + w1*Y + w2*Z + bb;
  }
}

// ---------------------------------------------------------------------------
// Split-K kNN body, BRANCHLESS batch-network edition (round-13).
// 4 threads/query (t: ql=t>>2, h=t&3), thread h scans candidates == h (mod 4).
// Per 8-candidate batch: pack u64 keys (sortable-f32(d)<<32)|idx, bitonic
// sort-8, min-inject into sorted A[16], bitonic-merge-16. u64 order == lex
// (d, idx) == top_k tie-break exactly; no divergent insert chain at all
// (the old exec-masked bubble ran ~always at wave level -- union over 64
// lanes defeats per-lane gating). Leader then 4-way-merges sorted u64 lists.
// smem: max(NK*4, QB*130) floats (QB=64 -> 8320).
template<int NK, int QB>
DEV void knn_body(float* smem, const float* __restrict__ qxyz,
                  const float* __restrict__ kxyz, int Nq,
                  int* __restrict__ oidx, int bx, int b){
  float4* kd = (float4*)smem;
  u64* lbuf  = (u64*)smem;               // list region (after kd is dead)
  int t = threadIdx.x;
  for (int i=t; i<NK; i+=256){
    const float* p = kxyz + ((size_t)b*NK + i)*3;
    float X=p[0], Y=p[1], Z=p[2];
    float sk = __fadd_rn(__fadd_rn(__fmul_rn(X,X),__fmul_rn(Y,Y)),__fmul_rn(Z,Z));
    kd[i] = make_float4(X,Y,Z,sk);
  }
  __syncthreads();
  int ql = t>>2, h = t&3;
  int q0 = bx*QB;
  const float* qp = qxyz + ((size_t)b*Nq + q0 + ql)*3;
  float QX=qp[0], QY=qp[1], QZ=qp[2];
  float sq = __fadd_rn(__fadd_rn(__fmul_rn(QX,QX),__fmul_rn(QY,QY)),__fmul_rn(QZ,QZ));
  u64 A[16];
  #pragma unroll
  for (int j=0;j<16;++j) A[j] = ~0ULL;
  #pragma unroll 1
  for (int i=0; i<NK/4; i+=8){
    u64 k8[8];
    #pragma unroll
    for (int u=0;u<8;++u){
      int cidx = 4*(i+u)+h;
      float4 c = kd[cidx];
      float dot = __fadd_rn(__fadd_rn(__fmul_rn(QX,c.x),__fmul_rn(QY,c.y)),__fmul_rn(QZ,c.z));
      float d = __fsub_rn(__fadd_rn(sq, c.w), __fmul_rn(2.0f,dot));
      k8[u] = ((u64)f2sort(d)<<32) | (unsigned)cidx;
    }
    sort8(k8);
    // inject: lower half of first bitonic-32 stage vs A(asc)++rev(k8)(desc)
    #pragma unroll
    for (int s=0;s<8;++s){
      u64 bb = k8[7-s];
      u64 a  = A[8+s];
      A[8+s] = (bb < a) ? bb : a;
    }
    bm16(A);                              // re-sort bitonic A ascending
  }
  __syncthreads();                        // kd dead; reuse smem for lists
  u64* Lq = lbuf + ((size_t)ql*65 + (size_t)h*16);   // stride 65 u64: bank-safe
  #pragma unroll
  for (int j=0;j<16;++j) Lq[j] = A[j];
  __syncthreads();
  if (t < QB){
    const u64* db = lbuf + (size_t)t*65;
    int p0=0,p1=0,p2=0,p3=0;
    u64 e0=db[0], e1=db[16], e2=db[32], e3=db[48];
    int* op = oidx + ((size_t)b*Nq + q0 + t)*16;
    #pragma unroll 1
    for (int j=0;j<16;++j){
      u64 bd = e0; int bh = 0;
      if (e1 < bd){ bd=e1; bh=1; }
      if (e2 < bd){ bd=e2; bh=2; }
      if (e3 < bd){ bd=e3; bh=3; }
      op[j] = (int)(unsigned)bd;
      if      (bh==0){ p0++; e0 = (p0<16)? db[p0]    : ~0ULL; }
      else if (bh==1){ p1++; e1 = (p1<16)? db[16+p1] : ~0ULL; }
      else if (bh==2){ p2++; e2 = (p2<16)? db[32+p2] : ~0ULL; }
      else           { p3++; e3 = (p3<16)? db[48+p3] : ~0ULL; }
    }
  }
  __syncthreads();                        // safe smem handoff (fused callers)
}

// ---------------------------------------------------------------------------
// FPS body (256 threads, 4 waves, one barrier per step) — round-9 structure.
// Packed u64 argmax key (fbits(dist)<<32)|(~idx); DPP chain to lane 63;
// winner coords carried through the scan; parity double-buffered LDS slots.
// smem: NP*4 + 48 + G floats. Exact fp32 no-FMA math.
template<int NP,int G>
DEV void fps_body(float* smem, const float* __restrict__ xyz,
                  int* __restrict__ oidx, float* __restrict__ oxyz, int b){
  constexpr int PPT = NP/256;
  __builtin_amdgcn_s_setprio(3);
  float4* xl4 = (float4*)smem;
  u64* candK = (u64*)(smem + NP*4);                 // [8] (2 par x 4 waves)
  float4* candX = (float4*)(smem + NP*4 + 16);      // [8]
  int* selidx = (int*)(smem + NP*4 + 48);           // [G]
  int t = threadIdx.x, w = t>>6;
  float px[PPT], py[PPT], pz[PPT], dist[PPT];
  #pragma unroll
  for (int j=0;j<PPT;++j){
    int gi = t + j*256;
    const float* p = xyz + ((size_t)b*NP + gi)*3;
    float X=p[0], Y=p[1], Z=p[2];
    px[j]=X; py[j]=Y; pz[j]=Z; dist[j]=1e10f;
    xl4[gi] = make_float4(X,Y,Z,0.f);
  }
  if (t==0) selidx[0] = 0;
  __syncthreads();
  float4 c0 = xl4[0];
  float cx=c0.x, cy=c0.y, cz=c0.z;
  int Bi = 0;
  for (int g=1; g<G; ++g){
    float bv=-1.f; int bi=0; float bxc=0.f, byc=0.f, bzc=0.f;
    #pragma unroll
    for (int j=0;j<PPT;++j){
      float dx=__fsub_rn(px[j],cx), dy=__fsub_rn(py[j],cy), dz=__fsub_rn(pz[j],cz);
      float d = __fadd_rn(__fadd_rn(__fmul_rn(dx,dx),__fmul_rn(dy,dy)),__fmul_rn(dz,dz));
      float nd = fminf(dist[j], d);
      dist[j] = nd;
      bool cc = (nd > bv);               // ascending idx in-lane: first-max kept
      bv = cc ? nd : bv;
      bi = cc ? (t + j*256) : bi;
      bxc = cc ? px[j] : bxc; byc = cc ? py[j] : byc; bzc = cc ? pz[j] : bzc;
    }
    u64 klocal = ((u64)__float_as_uint(bv) << 32) | (unsigned)(0xFFFFFFFFu - bi);
    u64 k = klocal;
    k = dpp_umax<0x111>(k);              // row_shr:1
    k = dpp_umax<0x112>(k);              // row_shr:2
    k = dpp_umax<0x114>(k);              // row_shr:4
    k = dpp_umax<0x118>(k);              // row_shr:8
    k = dpp_umax<0x142>(k);              // row_bcast15
    k = dpp_umax<0x143>(k);              // row_bcast31 -> lane 63 has wave max
    unsigned klo = (unsigned)__builtin_amdgcn_readlane((int)(unsigned)k, 63);
    unsigned khi = (unsigned)__builtin_amdgcn_readlane((int)(unsigned)(k>>32), 63);
    u64 wkey = ((u64)khi<<32) | klo;
    int par = g & 1;
    if (klocal == wkey){                 // exactly one lane per wave (idx in key)
      candK[par*4 + w] = wkey;
      candX[par*4 + w] = make_float4(bxc, byc, bzc, 0.f);
    }
    __syncthreads();
    u64 kk = candK[par*4+0]; float4 xx = candX[par*4+0];
    u64 k1 = candK[par*4+1]; float4 x1 = candX[par*4+1];
    if (k1 > kk){ kk=k1; xx=x1; }
    u64 k2 = candK[par*4+2]; float4 x2 = candX[par*4+2];
    if (k2 > kk){ kk=k2; xx=x2; }
    u64 k3 = candK[par*4+3]; float4 x3 = candX[par*4+3];
    if (k3 > kk){ kk=k3; xx=x3; }
    Bi = (int)(0xFFFFFFFFu - (unsigned)kk);
    cx = xx.x; cy = xx.y; cz = xx.z;
    if (t==0) selidx[g] = Bi;
  }
  __syncthreads();
  for (int i=t; i<G; i+=256){
    int s = selidx[i];
    float4 c = xl4[s];
    oidx[(size_t)b*G + i] = s;
    float* op = oxyz + ((size_t)b*G + i)*3;
    op[0]=c.x; op[1]=c.y; op[2]=c.z;
  }
}

// ---------------------------------------------------------------------------
// EdgeConv pre-norm body (256 threads). See round-3 notes.
template<int CF,int COUT,int QB>
DEV void edge_body(float* smem, const float* __restrict__ fk,
                   const int* __restrict__ sel, const int* __restrict__ knn,
                   const float* __restrict__ w, float* __restrict__ mm,
                   float* __restrict__ stats, int Nq, int Nk, int bx, int b){
  constexpr int CIN = 2*CF;
  constexpr int GPQ = COUT/2;
  constexpr int WS  = COUT+1;
  constexpr int ESTR= CF*16+8;
  constexpr int WTB = ((CF*WS+3)&~3);
  static_assert(QB*GPQ == 256, "block mapping");
  float* wtb = smem;
  float* e   = smem + WTB;
  float* fqs = e + QB*ESTR;
  float* sS  = fqs + QB*CF;
  int t = threadIdx.x;
  int q0 = bx*QB;

  if (t<8) sS[t]=0.f;
  for (int i=t; i<QB*CF; i+=256){
    int ql = i/CF, c = i&(CF-1);
    int qi = sel ? sel[b*Nq + q0 + ql] : (q0 + ql);
    fqs[i] = fk[((size_t)b*Nk + qi)*CF + c];
  }
  for (int i=t; i<CF*COUT; i+=256){
    int o = i/CF, c = i&(CF-1);
    wtb[c*WS+o] = w[o*CIN + c];
  }
  if (t < QB*16){
    int ql = t>>4, k = t&15;
    int nid = knn[((size_t)b*Nq + q0 + ql)*16 + k];
    const float4* row = (const float4*)(fk + ((size_t)b*Nk + nid)*CF);
    float* ep = e + ql*ESTR + k;
    #pragma unroll
    for (int c4=0; c4<CF/4; ++c4){
      float4 v = row[c4];
      ep[(c4*4+0)*16]=v.x; ep[(c4*4+1)*16]=v.y; ep[(c4*4+2)*16]=v.z; ep[(c4*4+3)*16]=v.w;
    }
  }
  __syncthreads();

  int ql = t/GPQ, o = t%GPQ;
  const float* eb = e + ql*ESTR;
  const float* fqb = fqs + ql*CF;
  float y0[16], y1[16];
  #pragma unroll
  for (int k=0;k<16;++k){ y0[k]=0.f; y1[k]=0.f; }
  float zA0=0.f, zA1=0.f;
  for (int c=0;c<CF;++c){
    float w0 = wtb[c*WS+o];
    float w1 = wtb[c*WS+o+GPQ];
    float fqc = fqb[c];
    zA0 = fmaf(w0,fqc,zA0); zA1 = fmaf(w1,fqc,zA1);
    const float4* ev4 = (const float4*)(eb + c*16);
    #pragma unroll
    for (int k4=0;k4<4;++k4){
      float4 ev = ev4[k4];
      y0[k4*4+0]=fmaf(w0,ev.x,y0[k4*4+0]); y0[k4*4+1]=fmaf(w0,ev.y,y0[k4*4+1]);
      y0[k4*4+2]=fmaf(w0,ev.z,y0[k4*4+2]); y0[k4*4+3]=fmaf(w0,ev.w,y0[k4*4+3]);
      y1[k4*4+0]=fmaf(w1,ev.x,y1[k4*4+0]); y1[k4*4+1]=fmaf(w1,ev.y,y1[k4*4+1]);
      y1[k4*4+2]=fmaf(w1,ev.z,y1[k4*4+2]); y1[k4*4+3]=fmaf(w1,ev.w,y1[k4*4+3]);
    }
  }
  __syncthreads();
  for (int i=t; i<CF*COUT; i+=256){
    int oo = i/CF, c = i&(CF-1);
    wtb[c*WS+oo] = w[oo*CIN + CF + c];
  }
  __syncthreads();
  float zB0=0.f, zB1=0.f;
  for (int c=0;c<CF;++c){
    float fqc = fqb[c];
    zB0 = fmaf(wtb[c*WS+o],fqc,zB0);
    zB1 = fmaf(wtb[c*WS+o+GPQ],fqc,zB1);
  }
  float z0 = zB0 - zA0, z1 = zB1 - zA1;

  float mx0=-3.4e38f, mn0=3.4e38f, s0=0.f, q0s=0.f;
  float mx1=-3.4e38f, mn1=3.4e38f, s1=0.f, q1s=0.f;
  #pragma unroll
  for (int k=0;k<16;++k){
    float v0 = y0[k]+z0, v1 = y1[k]+z1;
    mx0=fmaxf(mx0,v0); mn0=fminf(mn0,v0); s0+=v0; q0s=fmaf(v0,v0,q0s);
    mx1=fmaxf(mx1,v1); mn1=fminf(mn1,v1); s1+=v1; q1s=fmaf(v1,v1,q1s);
  }
  int g0 = o/(COUT/4);
  atomicAdd(&sS[g0],   s0); atomicAdd(&sS[4+g0],   q0s);
  atomicAdd(&sS[g0+2], s1); atomicAdd(&sS[6+g0],   q1s);
  size_t mi0 = ((size_t)b*Nq + q0 + ql)*COUT + o;
  ((float2*)mm)[mi0]       = make_float2(mx0,mn0);
  ((float2*)mm)[mi0+GPQ]   = make_float2(mx1,mn1);
  __syncthreads();
  if (t<8){
    int g = t>>1, which = t&1;
    float val = which ? sS[4+g] : sS[g];
    atomicAdd(&stats[(((size_t)b*4+g)*8 + (bx&7))*2 + which], val);
  }
}

// ---------------------------------------------------------------------------
// coor body: write (B,3,128) output from xyz2.
DEV void coor_body(const float* __restrict__ xyz2, void* __restrict__ outbase,
                   const int* __restrict__ flag, int bx){
  int i = bx*256 + threadIdx.x;          // 32*3*128 = 12288
  if (i >= 12288) return;
  int m = i & 127;
  int c = (i>>7) % 3;
  int b = i / 384;
  float v = xyz2[((size_t)b*128+m)*3 + c];
  if (*flag) ((float*)outbase)[i] = v;
  else       ((unsigned short*)outbase)[i] = f2bf(v);
}

// ---------------------------------------------------------------------------
// Fused launches: FPS blocks first; independent knn/edge work fills the rest.
__global__ __launch_bounds__(256,4) void fused1_kernel(
    const float* __restrict__ xyz0, int* __restrict__ knnb1,
    int* __restrict__ idx1, float* __restrict__ xyz1){
  __shared__ __align__(16) float smem[8752];   // fps1 8752 > knn 8320
  int bx = blockIdx.x;
  if (bx < 32){
    fps_body<2048,512>(smem, xyz0, idx1, xyz1, bx);
  } else {
    int rid = bx - 32;                          // 1024 knn1 blocks
    knn_body<2048,64>(smem, xyz0, xyz0, 2048, knnb1, rid & 31, rid >> 5);
  }
}

__global__ __launch_bounds__(256,4) void fused2_kernel(
    const float* __restrict__ xyz0, const float* __restrict__ xyz1,
    const int* __restrict__ knnb1,
    int* __restrict__ knnb2, int* __restrict__ knnb3,
    int* __restrict__ idx2, float* __restrict__ xyz2,
    const float* __restrict__ f0, const float* __restrict__ cw1,
    float* __restrict__ mmb, float* __restrict__ stats1){
  __shared__ __align__(16) float smem[8320];   // knn 8320 > edge1 2576 > fps2 2224
  int bx = blockIdx.x;
  if (bx < 32){
    fps_body<512,128>(smem, xyz1, idx2, xyz2, bx);
  } else if (bx < 288){
    int rid = bx - 32;                          // 256 knn2 blocks
    knn_body<2048,64>(smem, xyz1, xyz0, 512, knnb2, rid & 7, rid >> 3);
  } else if (bx < 544){
    int rid = bx - 288;                         // 256 knn3 blocks
    knn_body<512,64>(smem, xyz1, xyz1, 512, knnb3, rid & 7, rid >> 3);
  } else {
    int rid = bx - 544;                         // 4096 edge1 blocks
    edge_body<8,32,16>(smem, f0, nullptr, knnb1, cw1, mmb, stats1,
                       2048, 2048, rid & 127, rid >> 7);
  }
}

// fused3: knn4 (64) || edge2 (2048) || coor (48). All deps ready after fin1.
__global__ __launch_bounds__(256,4) void fused3_kernel(
    const float* __restrict__ xyz1, const float* __restrict__ xyz2,
    int* __restrict__ knnb4,
    const float* __restrict__ f1, const int* __restrict__ idx1,
    const int* __restrict__ knnb2, const float* __restrict__ cw2,
    float* __restrict__ mmb, float* __restrict__ stats2,
    void* __restrict__ outbase, const int* __restrict__ flag){
  __shared__ __align__(16) float smem[8320];   // knn 8320 > edge2 6504
  int bx = blockIdx.x;
  if (bx < 64){
    knn_body<512,64>(smem, xyz2, xyz1, 128, knnb4, bx & 1, bx >> 1);
  } else if (bx < 2112){
    int rid = bx - 64;                          // 2048 edge2 blocks
    edge_body<32,64,8>(smem, f1, idx1, knnb2, cw2, mmb, stats2,
                       512, 2048, rid & 63, rid >> 6);
  } else {
    coor_body(xyz2, outbase, flag, bx - 2112);  // 48 coor blocks
  }
}

template<int CF,int COUT,int QB>
__global__ __launch_bounds__(256) void edge_kernel(
    const float* __restrict__ fk, const int* __restrict__ sel,
    const int* __restrict__ knn, const float* __restrict__ w,
    float* __restrict__ mm, float* __restrict__ stats, int Nq, int Nk){
  constexpr int WS  = COUT+1;
  constexpr int ESTR= CF*16+8;
  constexpr int WTB = ((CF*WS+3)&~3);
  constexpr int SM  = WTB + QB*ESTR + QB*CF + 8;
  __shared__ __align__(16) float smem[SM];
  edge_body<CF,COUT,QB>(smem, fk, sel, knn, w, mm, stats, Nq, Nk,
                        blockIdx.x, blockIdx.y);
}

// ---------------------------------------------------------------------------
// finalize: sum stat buckets, GN affine on max (min if a<0) + LeakyReLU.
__global__ __launch_bounds__(256) void fin_kernel(
    const float* __restrict__ mm, const float* __restrict__ stats,
    const float* __restrict__ gam, const float* __restrict__ bet,
    float* __restrict__ fo, void* __restrict__ outbase, const int* __restrict__ flag,
    int outoff, int Nq, int COUT, float invcnt, int total){
  for (int i = blockIdx.x*256 + threadIdx.x; i<total; i += gridDim.x*256){
    int o = i % COUT;
    int r = i / COUT;
    int q = r % Nq;
    int b = r / Nq;
    int g = o / (COUT>>2);
    const float* sp = stats + ((size_t)(b*4+g))*16;
    float s=0.f, s2=0.f;
    #pragma unroll
    for (int nb=0;nb<8;++nb){ s += sp[nb*2]; s2 += sp[nb*2+1]; }
    float mean = s*invcnt;
    float var  = fmaxf(s2*invcnt - mean*mean, 0.f);
    float inv  = 1.0f / sqrtf(var + 1e-5f);
    float a  = gam[o] * inv;
    float bb = bet[o] - a*mean;
    const float* mp = mm + (size_t)i*2;
    float xv = (a>=0.f) ? mp[0] : mp[1];  // monotone affine: max commutes
    float v = fmaf(a, xv, bb);
    v = (v>=0.f) ? v : 0.2f*v;
    if (fo) fo[i]=v;
    if (outbase){
      int idx = outoff + ((b*COUT + o)*Nq + q);
      if (*flag) ((float*)outbase)[idx] = v;
      else       ((unsigned short*)outbase)[idx] = f2bf(v);
    }
  }
}

// ---------------------------------------------------------------------------
extern "C" void kernel_launch(void* const* d_in, const int* in_sizes, int n_in,
                              void* d_out, int out_size, void* d_ws, size_t ws_size,
                              hipStream_t stream){
  float* W    = (float*)d_ws;
  float* xyz0 = W;                      // 196608
  float* f0   = W + 196608;             // 524288
  float* f1   = W + 720896;             // 2097152
  float* xyz1 = W + 2818048;            // 49152
  float* f2   = W + 2867200;            // 1048576
  float* f3   = W + 3915776;            // 1048576
  float* xyz2 = W + 4964352;            // 12288
  float* stats= W + 4976640;            // 8192
  int*   flag = (int*)(W + 4984832);    // 16 (pad)
  float* PRM  = W + 4984848;            // 29792 canonical fp32 params
  int*  idx1  = (int*)(W + 5014640);    // 16384
  int*  idx2  = (int*)(W + 5031024);    // 4096
  float* SCR  = W + 5035120;            // aliased per-layer scratch
  int*   knnb = (int*)SCR;              // knn1: 1048576 ints (dead after fused2)
  int*   knnb4= (int*)SCR;              // knn4 reuses knn1 region
  int*   knnb2= (int*)f3;               // knn2: 262144 ints in f3 (dead at fin3)
  int*   knnb3= (int*)f3 + 262144;      // knn3: 262144 ints in f3
  float* mmb  = SCR + 1048576;          // <= 4194304 floats

  float* cw_in = PRM;          // 24
  float* cb_in = PRM+24;       // 8
  float* cw1 = PRM+32;   float* cg1 = PRM+544;   float* cbb1 = PRM+576;
  float* cw2 = PRM+608;  float* cg2 = PRM+4704;  float* cbb2 = PRM+4768;
  float* cw3 = PRM+4832; float* cg3 = PRM+13024; float* cbb3 = PRM+13088;
  float* cw4 = PRM+13152;float* cg4 = PRM+29536; float* cbb4 = PRM+29664;

  PConv pc;
  const int psz[14] = {24,8,512,32,32,4096,64,64,8192,64,64,16384,128,128};
  float* pdst[14] = {cw_in,cb_in,cw1,cg1,cbb1,cw2,cg2,cbb2,cw3,cg3,cbb3,cw4,cg4,cbb4};
  for (int j=0;j<14;++j){ pc.s[j]=d_in[j+1]; pc.d[j]=pdst[j]; pc.sz[j]=psz[j]; }

  // prep: per-block dtype detect + param conversion + coords/f0/stats
  prep_kernel<<<373,256,0,stream>>>(d_in[0], flag, d_in[1], d_in[2], pc,
                                    xyz0, f0, stats);

  // ---- fused1: FPS 2048->512 (32 blocks) || knn1 (1024 blocks)
  fused1_kernel<<<1056,256,0,stream>>>(xyz0, knnb, idx1, xyz1);

  // ---- fused2: FPS 512->128 (32) || knn2 (256) || knn3 (256) || edge1 (4096)
  fused2_kernel<<<4640,256,0,stream>>>(xyz0, xyz1, knnb, knnb2, knnb3,
                                       idx2, xyz2, f0, cw1, mmb, stats+0);

  // ---- layer 1 finalize
  fin_kernel<<<1024,256,0,stream>>>(mmb, stats+0, cg1, cbb1, f1, nullptr, flag, 0, 2048, 32, 1.f/262144.f, 2097152);

  // ---- fused3: knn4 (64) || edge2 (2048) || coor (48)
  fused3_kernel<<<2160,256,0,stream>>>(xyz1, xyz2, knnb4,
                                       f1, idx1, knnb2, cw2, mmb, stats+2048,
                                       d_out, flag);
  fin_kernel<<<1024,256,0,stream>>>(mmb, stats+2048, cg2, cbb2, f2, nullptr, flag, 0, 512, 64, 1.f/131072.f, 1048576);

  // ---- layer 3: 512q/512k, 128 -> 64
  edge_kernel<64,64,8><<<dim3(64,32),256,0,stream>>>(f2, nullptr, knnb3, cw3, mmb, stats+4096, 512, 512);
  fin_kernel<<<1024,256,0,stream>>>(mmb, stats+4096, cg3, cbb3, f3, nullptr, flag, 0, 512, 64, 1.f/131072.f, 1048576);

  // ---- layer 4: 128q/512k, 128 -> 128 -> final f output
  edge_kernel<64,128,4><<<dim3(32,32),256,0,stream>>>(f3, idx2, knnb4, cw4, mmb, stats+6144, 128, 512);
  fin_kernel<<<1024,256,0,stream>>>(mmb, stats+6144, cg4, cbb4, nullptr, d_out, flag, 12288, 128, 128, 1.f/65536.f, 524288);
}